// Round 1
// baseline (444.181 us; speedup 1.0000x reference)
//
#include <hip/hip_runtime.h>
#include <hip/hip_bf16.h>
#include <cstdint>
#include <cstddef>

typedef unsigned short u16;
typedef __attribute__((ext_vector_type(8))) __bf16 bf16x8;
typedef __attribute__((ext_vector_type(4))) float f32x4;

__device__ __forceinline__ u16 f2b(float f) {
  __hip_bfloat16 h = __float2bfloat16(f);
  return *reinterpret_cast<u16*>(&h);
}
__device__ __forceinline__ float b2f(u16 u) {
  union { float f; uint32_t i; } x; x.i = ((uint32_t)u) << 16; return x.f;
}
__device__ __forceinline__ f32x4 mfma16(bf16x8 a, bf16x8 b, f32x4 c) {
  return __builtin_amdgcn_mfma_f32_16x16x32_bf16(a, b, c, 0, 0, 0);
}
__device__ __forceinline__ void async16(const void* g, void* l) {
  __builtin_amdgcn_global_load_lds((const __attribute__((address_space(1))) uint32_t*)g,
                                   (__attribute__((address_space(3))) uint32_t*)l, 16, 0, 0);
}

// ---------------------------------------------------------------------------
// Weight conversion: fc_w1 (256x8000) permuted k: out[j][t*32+c2] = w[j][c2*250+t]
__global__ __launch_bounds__(256) void w1_perm(const float* __restrict__ w,
                                               u16* __restrict__ o) {
  __shared__ float L[8000];
  int j = blockIdx.x, tid = threadIdx.x;
  for (int i = tid; i < 8000; i += 256) L[i] = w[(size_t)j * 8000 + i];
  __syncthreads();
  for (int i = tid; i < 8000; i += 256) {
    int tt = i >> 5, c2 = i & 31;
    o[(size_t)j * 8000 + i] = f2b(L[c2 * 250 + tt]);
  }
}

struct CvtArgs {
  const float* src[7];
  u16* dst[7];
  int cum[8];
};
__global__ __launch_bounds__(256) void f2b_multi(CvtArgs a, float* stats) {
  int i = blockIdx.x * 256 + threadIdx.x;
  if (blockIdx.x == 0 && threadIdx.x < 128) stats[threadIdx.x] = 0.f;
  int seg = 0;
  #pragma unroll
  for (int s = 1; s < 7; ++s) if (i >= a.cum[s]) seg = s;
  if (i < a.cum[7]) {
    int off = i - a.cum[seg];
    a.dst[seg][off] = f2b(a.src[seg][off]);
  }
}

// ---------------------------------------------------------------------------
// Fused conv1 (fp32) + conv2 (bf16 MFMA, im2col in LDS). One block per row.
// x out layout: x[row][t*32 + c2]  (matches permuted fc_w1)
__global__ __launch_bounds__(256) void conv_fused(
    const float* __restrict__ scan, const float* __restrict__ cw1,
    const float* __restrict__ cb1, const float* __restrict__ cw2,
    const float* __restrict__ cb2, u16* __restrict__ x, int row0) {
  __shared__ float s[256];
  __shared__ __align__(16) u16 h1T[258 * 32];  // [p][c1], bf16
  __shared__ __align__(16) u16 w2r[32 * 96];   // [c2][k*32+c1], bf16
  int tid = threadIdx.x;
  int lrow = blockIdx.x;
  s[tid] = scan[(size_t)(row0 + lrow) * 256 + tid];
  for (int i = tid; i < 3072; i += 256) {
    int c2 = i / 96, rem = i - c2 * 96, k = rem >> 5, c1 = rem & 31;
    w2r[i] = f2b(cw2[(c2 * 32 + c1) * 3 + k]);
  }
  if (tid < 192) h1T[252 * 32 + tid] = 0;  // zero pad rows 252..257
  __syncthreads();
  {  // conv1: h1T[p][c1] = relu(sum_k s[p+k]*w1[c1][k] + b1[c1]), p<252
    int c1 = tid & 31, pb = tid >> 5;
    float w0 = cw1[c1 * 5 + 0], w1v = cw1[c1 * 5 + 1], w2v = cw1[c1 * 5 + 2],
          w3v = cw1[c1 * 5 + 3], w4v = cw1[c1 * 5 + 4];
    float bb = cb1[c1];
    int p0 = pb * 32;
    #pragma unroll 4
    for (int i = 0; i < 32; ++i) {
      int p = p0 + i;
      if (p < 252) {
        float a = bb + s[p] * w0 + s[p + 1] * w1v + s[p + 2] * w2v +
                  s[p + 3] * w3v + s[p + 4] * w4v;
        h1T[p * 32 + c1] = f2b(fmaxf(a, 0.f));
      }
    }
  }
  __syncthreads();
  // conv2 via MFMA: out[t][c2] = sum_{kk<3, c1<32} h1T[t+kk][c1] * w2r[c2][kk*32+c1]
  int lane = tid & 63, wv = tid >> 6;
  int l15 = lane & 15, quad = lane >> 4;
  f32x4 zero = {0.f, 0.f, 0.f, 0.f};
  f32x4 acc[4][2];
  #pragma unroll
  for (int i = 0; i < 4; ++i) { acc[i][0] = zero; acc[i][1] = zero; }
  #pragma unroll
  for (int kk = 0; kk < 3; ++kk) {
    bf16x8 b0 = *(const bf16x8*)&w2r[l15 * 96 + kk * 32 + quad * 8];
    bf16x8 b1 = *(const bf16x8*)&w2r[(16 + l15) * 96 + kk * 32 + quad * 8];
    #pragma unroll
    for (int i = 0; i < 4; ++i) {
      int t = (wv * 4 + i) * 16 + l15 + kk;
      bf16x8 a = *(const bf16x8*)&h1T[t * 32 + quad * 8];
      acc[i][0] = mfma16(a, b0, acc[i][0]);
      acc[i][1] = mfma16(a, b1, acc[i][1]);
    }
  }
  float bias0 = cb2[l15], bias1 = cb2[16 + l15];
  u16* xr = x + (size_t)lrow * 8000;
  #pragma unroll
  for (int i = 0; i < 4; ++i) {
    int tb = (wv * 4 + i) * 16 + quad * 4;
    #pragma unroll
    for (int r = 0; r < 4; ++r) {
      int t = tb + r;
      if (t < 250) {
        xr[t * 32 + l15]      = f2b(fmaxf(acc[i][0][r] + bias0, 0.f));
        xr[t * 32 + 16 + l15] = f2b(fmaxf(acc[i][1][r] + bias1, 0.f));
      }
    }
  }
}

// ---------------------------------------------------------------------------
// Generic NT bf16 MFMA GEMM: out[m][n] = act(sum_k A[m][k]*W[n][k] + bias[n])
// MODE 0: raw fp32 store (split-K partials, z picks K-chunk and out buffer)
// MODE 1: +bias, relu, bf16 out.  MODE 2: +bias, leaky, bf16.  MODE 3: bf16 raw.
template <int MODE>
__global__ __launch_bounds__(256) void gemm_bt(
    const u16* __restrict__ A, int lda, const u16* __restrict__ W,
    const float* __restrict__ bias, float* __restrict__ outF,
    u16* __restrict__ outB, int ldo, int ksteps, int wq_sel, size_t out_zoff) {
  __shared__ __align__(16) u16 As[128 * 32];
  __shared__ __align__(16) u16 Bs[128 * 32];
  int tid = threadIdx.x;
  int m0 = blockIdx.y * 128, n0 = blockIdx.x * 128;
  if (wq_sel) W += (size_t)(blockIdx.y >> 5) * wq_sel;
  int kbase = blockIdx.z * ksteps * 32;
  if (MODE == 0) outF += (size_t)blockIdx.z * out_zoff;
  const u16* Ap = A + (size_t)m0 * lda + kbase;
  const u16* Wp = W + (size_t)n0 * lda + kbase;
  int lane = tid & 63, wv = tid >> 6;
  int l15 = lane & 15, quad = lane >> 4;
  int wm = (wv >> 1) * 64, wn = (wv & 1) * 64;
  int r0 = tid >> 2, kc = (tid & 3) * 8;
  int r1 = (tid + 256) >> 2;
  f32x4 zero = {0.f, 0.f, 0.f, 0.f};
  f32x4 acc[4][4];
  #pragma unroll
  for (int i = 0; i < 4; ++i)
    #pragma unroll
    for (int j = 0; j < 4; ++j) acc[i][j] = zero;
  for (int ks = 0; ks < ksteps; ++ks) {
    __syncthreads();
    async16(Ap + (size_t)r0 * lda + kc, &As[tid * 8]);
    async16(Wp + (size_t)r0 * lda + kc, &Bs[tid * 8]);
    async16(Ap + (size_t)r1 * lda + kc, &As[(tid + 256) * 8]);
    async16(Wp + (size_t)r1 * lda + kc, &Bs[(tid + 256) * 8]);
    __syncthreads();
    bf16x8 af[4], bfr[4];
    #pragma unroll
    for (int i = 0; i < 4; ++i)
      af[i] = *(const bf16x8*)&As[(wm + i * 16 + l15) * 32 + quad * 8];
    #pragma unroll
    for (int j = 0; j < 4; ++j)
      bfr[j] = *(const bf16x8*)&Bs[(wn + j * 16 + l15) * 32 + quad * 8];
    #pragma unroll
    for (int i = 0; i < 4; ++i)
      #pragma unroll
      for (int j = 0; j < 4; ++j) acc[i][j] = mfma16(af[i], bfr[j], acc[i][j]);
    Ap += 32; Wp += 32;
  }
  #pragma unroll
  for (int i = 0; i < 4; ++i) {
    int mb = m0 + wm + i * 16 + quad * 4;
    #pragma unroll
    for (int j = 0; j < 4; ++j) {
      int n = n0 + wn + j * 16 + l15;
      float bv_ = (MODE == 1 || MODE == 2) ? bias[n] : 0.f;
      #pragma unroll
      for (int r = 0; r < 4; ++r) {
        float v = acc[i][j][r];
        if (MODE == 0) {
          outF[(size_t)(mb + r) * ldo + n] = v;
        } else {
          v += bv_;
          if (MODE == 1) v = fmaxf(v, 0.f);
          if (MODE == 2) v = v >= 0.f ? v : 0.01f * v;
          outB[(size_t)(mb + r) * ldo + n] = f2b(v);
        }
      }
    }
  }
}

// ---------------------------------------------------------------------------
// fc2 (relu(sum hparts + b1) @ w2^T + b2) + build inps rows + batch-stat partials
__global__ __launch_bounds__(256) void fc2_stats(
    const float* __restrict__ hparts, const float* __restrict__ b1,
    const float* __restrict__ w2, const float* __restrict__ b2,
    const float* __restrict__ obs, const float* __restrict__ acts,
    float* __restrict__ inps, float* __restrict__ stats) {
  __shared__ float hL[32 * 260];
  __shared__ float w2L[10 * 260];
  __shared__ float b1L[256];
  __shared__ float ipL[32 * 61];
  int tid = threadIdx.x, r0 = blockIdx.x * 32;
  b1L[tid] = b1[tid];
  for (int i = tid; i < 2560; i += 256) w2L[(i >> 8) * 260 + (i & 255)] = w2[i];
  for (int i = tid; i < 32 * 48; i += 256) {
    int r = i / 48, f = i - r * 48;
    ipL[r * 61 + f] = obs[(size_t)(r0 + r) * 48 + f];
  }
  if (tid < 64) {
    int r = tid >> 1, f = tid & 1;
    ipL[r * 61 + 48 + f] = acts[(size_t)(r0 + r) * 2 + f];
  }
  __syncthreads();
  const size_t HS = (size_t)12288 * 256;
  for (int i = tid; i < 32 * 256; i += 256) {
    int r = i >> 8, c = i & 255;
    size_t g = (size_t)(r0 + r) * 256 + c;
    float v = b1L[c] + hparts[g] + hparts[g + HS] + hparts[g + 2 * HS] +
              hparts[g + 3 * HS] + hparts[g + 4 * HS];
    hL[r * 260 + c] = fmaxf(v, 0.f);
  }
  __syncthreads();
  {
    int r = tid >> 3, ob = tid & 7;
    for (int o = ob; o < 10; o += 8) {
      float a = 0.f;
      #pragma unroll 8
      for (int c = 0; c < 256; ++c) a += hL[r * 260 + c] * w2L[o * 260 + c];
      ipL[r * 61 + 50 + o] = a + b2[o];
    }
  }
  __syncthreads();
  for (int i = tid; i < 32 * 60; i += 256) {
    int r = i / 60, f = i - r * 60;
    inps[(size_t)(r0 + r) * 64 + f] = ipL[r * 61 + f];
  }
  if (tid < 60) {
    float s = 0.f, s2 = 0.f;
    for (int r = 0; r < 32; ++r) {
      float v = ipL[r * 61 + tid];
      s += v; s2 += v * v;
    }
    atomicAdd(&stats[tid], s);
    atomicAdd(&stats[64 + tid], s2);
  }
}

// ---------------------------------------------------------------------------
// normalize + enc (60->128) + leaky -> sa (bf16)
__global__ __launch_bounds__(256) void enc_kernel(
    const float* __restrict__ inps, const float* __restrict__ stats,
    const float* __restrict__ enc_w, const float* __restrict__ enc_b,
    u16* __restrict__ sab) {
  __shared__ float ewL[128 * 61];
  __shared__ float nrm[32 * 61];
  __shared__ float ebL[128];
  __shared__ float muL[60], ivL[60];
  int tid = threadIdx.x, r0 = blockIdx.x * 32;
  if (tid < 128) ebL[tid] = enc_b[tid];
  if (tid < 60) {
    float s = stats[tid], s2 = stats[64 + tid];
    float mu = s * (1.f / 12288.f);
    float var = s2 * (1.f / 12288.f) - mu * mu;
    muL[tid] = mu;
    ivL[tid] = rsqrtf(var + 1e-5f);
  }
  for (int i = tid; i < 128 * 60; i += 256) {
    int h = i / 60, f = i - h * 60;
    ewL[h * 61 + f] = enc_w[i];
  }
  __syncthreads();
  for (int i = tid; i < 32 * 60; i += 256) {
    int r = i / 60, f = i - r * 60;
    nrm[r * 61 + f] = (inps[(size_t)(r0 + r) * 64 + f] - muL[f]) * ivL[f];
  }
  __syncthreads();
  for (int i = tid; i < 32 * 128; i += 256) {
    int r = i >> 7, h = i & 127;
    float a = ebL[h];
    #pragma unroll 4
    for (int f = 0; f < 60; ++f) a += nrm[r * 61 + f] * ewL[h * 61 + f];
    a = a >= 0.f ? a : 0.01f * a;
    sab[(size_t)(r0 + r) * 128 + h] = f2b(a);
  }
}

// ---------------------------------------------------------------------------
// attention combine: per-b softmax over other agents + emb = [sa | other] (bf16)
__global__ __launch_bounds__(128) void attn_combine(
    const u16* __restrict__ qb, const u16* __restrict__ keysb,
    const u16* __restrict__ valsb, const u16* __restrict__ sab,
    u16* __restrict__ emb) {
  __shared__ float qL[3][128], kL[3][128], vL[3][128];
  __shared__ float lg[3][8][3], wgt[3][8][3];
  int b = blockIdx.x, t = threadIdx.x;
  #pragma unroll
  for (int o = 0; o < 3; ++o) {
    size_t base = (size_t)(o * 4096 + b) * 128 + t;
    qL[o][t] = b2f(qb[base]);
    kL[o][t] = b2f(keysb[base]);
    vL[o][t] = b2f(valsb[base]);
  }
  __syncthreads();
  if (t < 72) {
    int g = t / 24, n = (t / 3) % 8, o = t % 3;
    float a = 0.f;
    #pragma unroll
    for (int d = 0; d < 16; ++d) a += qL[g][n * 16 + d] * kL[o][n * 16 + d];
    lg[g][n][o] = (o == g) ? -1e30f : a * 0.25f;
  }
  __syncthreads();
  if (t < 24) {
    int g = t / 8, n = t % 8;
    float m = fmaxf(fmaxf(lg[g][n][0], lg[g][n][1]), lg[g][n][2]);
    float e0 = expf(lg[g][n][0] - m), e1 = expf(lg[g][n][1] - m),
          e2 = expf(lg[g][n][2] - m);
    float inv = 1.f / (e0 + e1 + e2);
    wgt[g][n][0] = e0 * inv; wgt[g][n][1] = e1 * inv; wgt[g][n][2] = e2 * inv;
  }
  __syncthreads();
  int n = t >> 4, d = t & 15;
  #pragma unroll
  for (int g = 0; g < 3; ++g) {
    float o_ = wgt[g][n][0] * vL[0][n * 16 + d] +
               wgt[g][n][1] * vL[1][n * 16 + d] +
               wgt[g][n][2] * vL[2][n * 16 + d];
    size_t rbase = (size_t)(g * 4096 + b) * 256;
    emb[rbase + 128 + t] = f2b(o_);
    emb[rbase + t] = sab[(size_t)(g * 4096 + b) * 128 + t];
  }
}

// ---------------------------------------------------------------------------
// final layer: out[row] = t2 . w3 + b3 for both heads. One wave per row.
__global__ __launch_bounds__(256) void final_dot(
    const u16* __restrict__ t2a, const u16* __restrict__ t2b,
    const float* __restrict__ w3a, const float* __restrict__ b3a,
    const float* __restrict__ w3b, const float* __restrict__ b3b,
    float* __restrict__ out) {
  int wv = threadIdx.x >> 6, lane = threadIdx.x & 63;
  int row = blockIdx.x * 4 + wv;
  float sa_ = 0.f, sb_ = 0.f;
  #pragma unroll
  for (int e = 0; e < 4; ++e) {
    int c = lane * 4 + e;
    sa_ += b2f(t2a[(size_t)row * 256 + c]) * w3a[c];
    sb_ += b2f(t2b[(size_t)row * 256 + c]) * w3b[c];
  }
  #pragma unroll
  for (int off = 32; off; off >>= 1) {
    sa_ += __shfl_down(sa_, off);
    sb_ += __shfl_down(sb_, off);
  }
  if (lane == 0) {
    out[row] = sa_ + b3a[0];
    out[12288 + row] = sb_ + b3b[0];
  }
}

// ---------------------------------------------------------------------------
extern "C" void kernel_launch(void* const* d_in, const int* in_sizes, int n_in,
                              void* d_out, int out_size, void* d_ws,
                              size_t ws_size, hipStream_t stream) {
  const float* obs  = (const float*)d_in[0];
  const float* acts = (const float*)d_in[1];
  const float* scan = (const float*)d_in[2];
  const float* cw1  = (const float*)d_in[3];
  const float* cb1  = (const float*)d_in[4];
  const float* cw2  = (const float*)d_in[5];
  const float* cb2  = (const float*)d_in[6];
  const float* fw1  = (const float*)d_in[7];
  const float* fb1  = (const float*)d_in[8];
  const float* fw2  = (const float*)d_in[9];
  const float* fb2  = (const float*)d_in[10];
  const float* encw = (const float*)d_in[11];
  const float* encb = (const float*)d_in[12];
  const float* Wk   = (const float*)d_in[13];
  const float* Wv   = (const float*)d_in[14];
  const float* bv   = (const float*)d_in[15];
  const float* Wq   = (const float*)d_in[16];
  const float* q1w1 = (const float*)d_in[17];
  const float* q1b1 = (const float*)d_in[18];
  const float* q1w2 = (const float*)d_in[19];
  const float* q1b2 = (const float*)d_in[20];
  const float* q1w3 = (const float*)d_in[21];
  const float* q1b3 = (const float*)d_in[22];
  const float* q2w1 = (const float*)d_in[23];
  const float* q2b1 = (const float*)d_in[24];
  const float* q2w2 = (const float*)d_in[25];
  const float* q2b2 = (const float*)d_in[26];
  const float* q2w3 = (const float*)d_in[27];
  const float* q2b3 = (const float*)d_in[28];
  float* out = (float*)d_out;
  char* ws = (char*)d_ws;
  if (ws_size < 166003712u) return;  // need ~158 MB scratch

  // persistent region
  u16*   x     = (u16*)(ws + 0);           // slab: 6144*8000 bf16 = 98,304,000 B
  u16*   w1b   = (u16*)(ws + 98304000);    // 256*8000 bf16
  float* hpart = (float*)(ws + 102400000); // 5 * 12288*256 fp32 (split-K partials)
  float* stats = (float*)(ws + 165314560); // 128 sums + 128 sumsq (uses 60/60)
  u16*   wkb   = (u16*)(ws + 165315584);
  u16*   wvb   = (u16*)(ws + 165348352);
  u16*   wqb   = (u16*)(ws + 165381120);
  u16*   m1a   = (u16*)(ws + 165479424);
  u16*   m2a   = (u16*)(ws + 165610496);
  u16*   m1b   = (u16*)(ws + 165741568);
  u16*   m2b   = (u16*)(ws + 165872640);
  // region aliasing x (x is dead after the last fc1 GEMM)
  float* inps  = (float*)(ws + 0);         // 12288*64 fp32
  u16*   sab   = (u16*)(ws + 3145728);
  u16*   keysb = (u16*)(ws + 6291456);
  u16*   valsb = (u16*)(ws + 9437184);
  u16*   qb    = (u16*)(ws + 12582912);
  u16*   embb  = (u16*)(ws + 15728640);    // 12288*256 bf16
  u16*   t1a   = (u16*)(ws + 22020096);
  u16*   t2a   = (u16*)(ws + 28311552);
  u16*   t1b   = (u16*)(ws + 34603008);
  u16*   t2b   = (u16*)(ws + 40894464);

  w1_perm<<<256, 256, 0, stream>>>(fw1, w1b);
  CvtArgs ca;
  ca.src[0] = Wk;  ca.src[1] = Wv;  ca.src[2] = Wq;  ca.src[3] = q1w1;
  ca.src[4] = q1w2; ca.src[5] = q2w1; ca.src[6] = q2w2;
  ca.dst[0] = wkb; ca.dst[1] = wvb; ca.dst[2] = wqb; ca.dst[3] = m1a;
  ca.dst[4] = m2a; ca.dst[5] = m1b; ca.dst[6] = m2b;
  const int sz[7] = {16384, 16384, 49152, 65536, 65536, 65536, 65536};
  int cum = 0;
  ca.cum[0] = 0;
  for (int i = 0; i < 7; ++i) { cum += sz[i]; ca.cum[i + 1] = cum; }
  f2b_multi<<<1344, 256, 0, stream>>>(ca, stats);

  // conv + fc1 in 2 row slabs (x buffer holds one slab at a time)
  for (int s = 0; s < 2; ++s) {
    conv_fused<<<6144, 256, 0, stream>>>(scan, cw1, cb1, cw2, cb2, x, s * 6144);
    gemm_bt<0><<<dim3(2, 48, 5), 256, 0, stream>>>(
        x, 8000, w1b, nullptr, hpart + (size_t)s * 6144 * 256, nullptr, 256,
        50, 0, (size_t)12288 * 256);
  }
  fc2_stats<<<384, 256, 0, stream>>>(hpart, fb1, fw2, fb2, obs, acts, inps, stats);
  enc_kernel<<<384, 256, 0, stream>>>(inps, stats, encw, encb, sab);
  gemm_bt<3><<<dim3(1, 96, 1), 256, 0, stream>>>(sab, 128, wkb, nullptr, nullptr,
                                                 keysb, 128, 4, 0, 0);
  gemm_bt<2><<<dim3(1, 96, 1), 256, 0, stream>>>(sab, 128, wvb, bv, nullptr,
                                                 valsb, 128, 4, 0, 0);
  gemm_bt<3><<<dim3(1, 96, 1), 256, 0, stream>>>(sab, 128, wqb, nullptr, nullptr,
                                                 qb, 128, 4, 16384, 0);
  attn_combine<<<4096, 128, 0, stream>>>(qb, keysb, valsb, sab, embb);
  gemm_bt<1><<<dim3(2, 96, 1), 256, 0, stream>>>(embb, 256, m1a, q1b1, nullptr,
                                                 t1a, 256, 8, 0, 0);
  gemm_bt<1><<<dim3(2, 96, 1), 256, 0, stream>>>(t1a, 256, m2a, q1b2, nullptr,
                                                 t2a, 256, 8, 0, 0);
  gemm_bt<1><<<dim3(2, 96, 1), 256, 0, stream>>>(embb, 256, m1b, q2b1, nullptr,
                                                 t1b, 256, 8, 0, 0);
  gemm_bt<1><<<dim3(2, 96, 1), 256, 0, stream>>>(t1b, 256, m2b, q2b2, nullptr,
                                                 t2b, 256, 8, 0, 0);
  final_dot<<<3072, 256, 0, stream>>>(t2a, t2b, q1w3, q1b3, q2w3, q2b3, out);
}

// Round 2
// 414.523 us; speedup vs baseline: 1.0715x; 1.0715x over previous
//
#include <hip/hip_runtime.h>
#include <hip/hip_bf16.h>
#include <cstdint>
#include <cstddef>

typedef unsigned short u16;
typedef __attribute__((ext_vector_type(8))) __bf16 bf16x8;
typedef __attribute__((ext_vector_type(4))) float f32x4;

__device__ __forceinline__ u16 f2b(float f) {
  __hip_bfloat16 h = __float2bfloat16(f);
  return *reinterpret_cast<u16*>(&h);
}
__device__ __forceinline__ uint32_t pk2(float a, float b) {
  __hip_bfloat162 h = __float22bfloat162_rn(make_float2(a, b));
  return *reinterpret_cast<uint32_t*>(&h);
}
__device__ __forceinline__ float b2f(u16 u) {
  union { float f; uint32_t i; } x; x.i = ((uint32_t)u) << 16; return x.f;
}
__device__ __forceinline__ f32x4 mfma16(bf16x8 a, bf16x8 b, f32x4 c) {
  return __builtin_amdgcn_mfma_f32_16x16x32_bf16(a, b, c, 0, 0, 0);
}
__device__ __forceinline__ void async16(const void* g, void* l) {
  __builtin_amdgcn_global_load_lds((const __attribute__((address_space(1))) uint32_t*)g,
                                   (__attribute__((address_space(3))) uint32_t*)l, 16, 0, 0);
}

// ---------------------------------------------------------------------------
// Weight conversion: fc_w1 (256x8000) permuted k: out[j][t*32+c2] = w[j][c2*250+t]
__global__ __launch_bounds__(256) void w1_perm(const float* __restrict__ w,
                                               u16* __restrict__ o) {
  __shared__ float L[8000];
  int j = blockIdx.x, tid = threadIdx.x;
  for (int i = tid; i < 8000; i += 256) L[i] = w[(size_t)j * 8000 + i];
  __syncthreads();
  for (int i = tid; i < 8000; i += 256) {
    int tt = i >> 5, c2 = i & 31;
    o[(size_t)j * 8000 + i] = f2b(L[c2 * 250 + tt]);
  }
}

struct CvtArgs {
  const float* src[8];
  u16* dst[8];
  int cum[9];
};
// segments 0..6: straight f32->bf16; segment 7: conv_w2 permute ->
//   w2g[c2][kk*32+c1] = bf16(cw2[(c2*32+c1)*3+kk])
__global__ __launch_bounds__(256) void f2b_multi(CvtArgs a, float* stats) {
  int i = blockIdx.x * 256 + threadIdx.x;
  if (blockIdx.x == 0 && threadIdx.x < 128) stats[threadIdx.x] = 0.f;
  int seg = 0;
  #pragma unroll
  for (int s = 1; s < 8; ++s) if (i >= a.cum[s]) seg = s;
  if (i < a.cum[8]) {
    int off = i - a.cum[seg];
    if (seg == 7) {
      int c2 = off / 96, rem = off - c2 * 96, kk = rem >> 5, c1 = rem & 31;
      a.dst[7][off] = f2b(a.src[7][(c2 * 32 + c1) * 3 + kk]);
    } else {
      a.dst[seg][off] = f2b(a.src[seg][off]);
    }
  }
}

// ---------------------------------------------------------------------------
// Fused conv1 (fp32, register-blocked) + conv2 (bf16 MFMA) per scan row.
// x out layout: x[row][t*32 + c2]  (matches permuted fc_w1)
__global__ __launch_bounds__(256) void conv_fused(
    const float* __restrict__ scan, const float* __restrict__ cw1,
    const float* __restrict__ cb1, const u16* __restrict__ w2g,
    const float* __restrict__ cb2, u16* __restrict__ x, int row0) {
  __shared__ float s[260];
  __shared__ __align__(16) u16 h1T[258 * 40];  // [p][c1], stride 40 (bank-safe)
  int tid = threadIdx.x;
  int lrow = blockIdx.x;
  int lane = tid & 63, wv = tid >> 6;
  int l15 = lane & 15, quad = lane >> 4;
  s[tid] = scan[(size_t)(row0 + lrow) * 256 + tid];
  if (tid < 4) s[256 + tid] = 0.f;
  if (tid < 240) h1T[252 * 40 + tid] = 0;  // zero rows 252..257
  // preload conv2 weight fragments (A operand, m=c2): 6 KB, L1-hot
  bf16x8 wfrag[2][3];
  #pragma unroll
  for (int i = 0; i < 2; ++i)
    #pragma unroll
    for (int kk = 0; kk < 3; ++kk)
      wfrag[i][kk] = *(const bf16x8*)&w2g[(i * 16 + l15) * 96 + kk * 32 + quad * 8];
  float bias[2][4];
  #pragma unroll
  for (int i = 0; i < 2; ++i)
    #pragma unroll
    for (int r = 0; r < 4; ++r) bias[i][r] = cb2[i * 16 + quad * 4 + r];
  __syncthreads();
  {  // conv1: thread = (pr = tid>>4: p in [pr*16, pr*16+16)) x (cpair = tid&15)
    int cpair = tid & 15, pr = tid >> 4;
    int c0 = cpair * 2;
    float wA[5], wB[5];
    #pragma unroll
    for (int k = 0; k < 5; ++k) { wA[k] = cw1[c0 * 5 + k]; wB[k] = cw1[c0 * 5 + 5 + k]; }
    float bA = cb1[c0], bB = cb1[c0 + 1];
    float sv[20];
    int p0 = pr * 16;
    #pragma unroll
    for (int j = 0; j < 5; ++j) {
      f32x4 v = *(const f32x4*)&s[p0 + 4 * j];
      sv[4 * j] = v[0]; sv[4 * j + 1] = v[1]; sv[4 * j + 2] = v[2]; sv[4 * j + 3] = v[3];
    }
    #pragma unroll
    for (int ii = 0; ii < 16; ++ii) {
      float va = bA, vb = bB;
      #pragma unroll
      for (int k = 0; k < 5; ++k) {
        va += sv[ii + k] * wA[k];
        vb += sv[ii + k] * wB[k];
      }
      int p = p0 + ii;
      if (p < 252) {
        *(uint32_t*)&h1T[p * 40 + c0] = pk2(fmaxf(va, 0.f), fmaxf(vb, 0.f));
      }
    }
  }
  __syncthreads();
  // conv2 MFMA: D[c2][t] with A=w2 (m=c2), B=h1 (n=t)
  f32x4 zero = {0.f, 0.f, 0.f, 0.f};
  f32x4 acc[4][2];
  #pragma unroll
  for (int jj = 0; jj < 4; ++jj) { acc[jj][0] = zero; acc[jj][1] = zero; }
  #pragma unroll
  for (int kk = 0; kk < 3; ++kk) {
    #pragma unroll
    for (int jj = 0; jj < 4; ++jj) {
      int t = (wv * 4 + jj) * 16 + l15 + kk;
      bf16x8 h = *(const bf16x8*)&h1T[t * 40 + quad * 8];
      acc[jj][0] = mfma16(wfrag[0][kk], h, acc[jj][0]);
      acc[jj][1] = mfma16(wfrag[1][kk], h, acc[jj][1]);
    }
  }
  __syncthreads();  // h1T reads done; reuse buffer as xT[t][c2] stride 40
  #pragma unroll
  for (int jj = 0; jj < 4; ++jj) {
    int t = (wv * 4 + jj) * 16 + l15;
    if (t < 250) {
      #pragma unroll
      for (int i = 0; i < 2; ++i) {
        float v0 = fmaxf(acc[jj][i][0] + bias[i][0], 0.f);
        float v1 = fmaxf(acc[jj][i][1] + bias[i][1], 0.f);
        float v2 = fmaxf(acc[jj][i][2] + bias[i][2], 0.f);
        float v3 = fmaxf(acc[jj][i][3] + bias[i][3], 0.f);
        uint2 pr2; pr2.x = pk2(v0, v1); pr2.y = pk2(v2, v3);
        *(uint2*)&h1T[t * 40 + i * 16 + quad * 4] = pr2;
      }
    }
  }
  __syncthreads();
  u16* xr = x + (size_t)lrow * 8000;
  #pragma unroll
  for (int it = 0; it < 4; ++it) {
    int e0 = (it * 256 + tid) * 8;
    if (e0 < 8000) {
      int t = e0 >> 5, c8 = (e0 >> 3) & 3;
      bf16x8 v = *(const bf16x8*)&h1T[t * 40 + c8 * 8];
      *(bf16x8*)&xr[e0] = v;
    }
  }
}

// ---------------------------------------------------------------------------
// Generic NT bf16 MFMA GEMM: out[m][n] = act(sum_k A[m][k]*W[n][k] + bias[n])
// MODE 0: raw fp32 store (split-K partials). MODE 1: +bias relu bf16.
// MODE 2: +bias leaky bf16. MODE 3: bf16 raw.
template <int MODE>
__global__ __launch_bounds__(256) void gemm_bt(
    const u16* __restrict__ A, int lda, const u16* __restrict__ W,
    const float* __restrict__ bias, float* __restrict__ outF,
    u16* __restrict__ outB, int ldo, int ksteps, int wq_sel, size_t out_zoff) {
  __shared__ __align__(16) u16 As[128 * 32];
  __shared__ __align__(16) u16 Bs[128 * 32];
  int tid = threadIdx.x;
  int m0 = blockIdx.y * 128, n0 = blockIdx.x * 128;
  if (wq_sel) W += (size_t)(blockIdx.y >> 5) * wq_sel;
  int kbase = blockIdx.z * ksteps * 32;
  if (MODE == 0) outF += (size_t)blockIdx.z * out_zoff;
  const u16* Ap = A + (size_t)m0 * lda + kbase;
  const u16* Wp = W + (size_t)n0 * lda + kbase;
  int lane = tid & 63, wv = tid >> 6;
  int l15 = lane & 15, quad = lane >> 4;
  int wm = (wv >> 1) * 64, wn = (wv & 1) * 64;
  int r0 = tid >> 2, kc = (tid & 3) * 8;
  int r1 = (tid + 256) >> 2;
  f32x4 zero = {0.f, 0.f, 0.f, 0.f};
  f32x4 acc[4][4];
  #pragma unroll
  for (int i = 0; i < 4; ++i)
    #pragma unroll
    for (int j = 0; j < 4; ++j) acc[i][j] = zero;
  for (int ks = 0; ks < ksteps; ++ks) {
    __syncthreads();
    async16(Ap + (size_t)r0 * lda + kc, &As[tid * 8]);
    async16(Wp + (size_t)r0 * lda + kc, &Bs[tid * 8]);
    async16(Ap + (size_t)r1 * lda + kc, &As[(tid + 256) * 8]);
    async16(Wp + (size_t)r1 * lda + kc, &Bs[(tid + 256) * 8]);
    __syncthreads();
    bf16x8 af[4], bfr[4];
    #pragma unroll
    for (int i = 0; i < 4; ++i)
      af[i] = *(const bf16x8*)&As[(wm + i * 16 + l15) * 32 + quad * 8];
    #pragma unroll
    for (int j = 0; j < 4; ++j)
      bfr[j] = *(const bf16x8*)&Bs[(wn + j * 16 + l15) * 32 + quad * 8];
    #pragma unroll
    for (int i = 0; i < 4; ++i)
      #pragma unroll
      for (int j = 0; j < 4; ++j) acc[i][j] = mfma16(af[i], bfr[j], acc[i][j]);
    Ap += 32; Wp += 32;
  }
  #pragma unroll
  for (int i = 0; i < 4; ++i) {
    int mb = m0 + wm + i * 16 + quad * 4;
    #pragma unroll
    for (int j = 0; j < 4; ++j) {
      int n = n0 + wn + j * 16 + l15;
      float bv_ = (MODE == 1 || MODE == 2) ? bias[n] : 0.f;
      #pragma unroll
      for (int r = 0; r < 4; ++r) {
        float v = acc[i][j][r];
        if (MODE == 0) {
          outF[(size_t)(mb + r) * ldo + n] = v;
        } else {
          v += bv_;
          if (MODE == 1) v = fmaxf(v, 0.f);
          if (MODE == 2) v = v >= 0.f ? v : 0.01f * v;
          outB[(size_t)(mb + r) * ldo + n] = f2b(v);
        }
      }
    }
  }
}

// ---------------------------------------------------------------------------
// fc2 (relu(sum hparts + b1) @ w2^T + b2) + build inps rows + batch-stat partials
__global__ __launch_bounds__(256) void fc2_stats(
    const float* __restrict__ hparts, const float* __restrict__ b1,
    const float* __restrict__ w2, const float* __restrict__ b2,
    const float* __restrict__ obs, const float* __restrict__ acts,
    float* __restrict__ inps, float* __restrict__ stats) {
  __shared__ float hL[32 * 260];
  __shared__ float w2L[10 * 260];
  __shared__ float b1L[256];
  __shared__ float ipL[32 * 61];
  int tid = threadIdx.x, r0 = blockIdx.x * 32;
  b1L[tid] = b1[tid];
  for (int i = tid; i < 2560; i += 256) w2L[(i >> 8) * 260 + (i & 255)] = w2[i];
  for (int i = tid; i < 32 * 48; i += 256) {
    int r = i / 48, f = i - r * 48;
    ipL[r * 61 + f] = obs[(size_t)(r0 + r) * 48 + f];
  }
  if (tid < 64) {
    int r = tid >> 1, f = tid & 1;
    ipL[r * 61 + 48 + f] = acts[(size_t)(r0 + r) * 2 + f];
  }
  __syncthreads();
  const size_t HS = (size_t)12288 * 256;
  for (int i = tid; i < 32 * 256; i += 256) {
    int r = i >> 8, c = i & 255;
    size_t g = (size_t)(r0 + r) * 256 + c;
    float v = b1L[c] + hparts[g] + hparts[g + HS] + hparts[g + 2 * HS] +
              hparts[g + 3 * HS] + hparts[g + 4 * HS];
    hL[r * 260 + c] = fmaxf(v, 0.f);
  }
  __syncthreads();
  {
    int r = tid >> 3, ob = tid & 7;
    for (int o = ob; o < 10; o += 8) {
      float a = 0.f;
      #pragma unroll 8
      for (int c = 0; c < 256; ++c) a += hL[r * 260 + c] * w2L[o * 260 + c];
      ipL[r * 61 + 50 + o] = a + b2[o];
    }
  }
  __syncthreads();
  for (int i = tid; i < 32 * 60; i += 256) {
    int r = i / 60, f = i - r * 60;
    inps[(size_t)(r0 + r) * 64 + f] = ipL[r * 61 + f];
  }
  if (tid < 60) {
    float s = 0.f, s2 = 0.f;
    for (int r = 0; r < 32; ++r) {
      float v = ipL[r * 61 + tid];
      s += v; s2 += v * v;
    }
    atomicAdd(&stats[tid], s);
    atomicAdd(&stats[64 + tid], s2);
  }
}

// ---------------------------------------------------------------------------
// normalize + enc (60->128) + leaky -> sa (bf16)
__global__ __launch_bounds__(256) void enc_kernel(
    const float* __restrict__ inps, const float* __restrict__ stats,
    const float* __restrict__ enc_w, const float* __restrict__ enc_b,
    u16* __restrict__ sab) {
  __shared__ float ewL[128 * 61];
  __shared__ float nrm[32 * 61];
  __shared__ float ebL[128];
  __shared__ float muL[60], ivL[60];
  int tid = threadIdx.x, r0 = blockIdx.x * 32;
  if (tid < 128) ebL[tid] = enc_b[tid];
  if (tid < 60) {
    float s = stats[tid], s2 = stats[64 + tid];
    float mu = s * (1.f / 12288.f);
    float var = s2 * (1.f / 12288.f) - mu * mu;
    muL[tid] = mu;
    ivL[tid] = rsqrtf(var + 1e-5f);
  }
  for (int i = tid; i < 128 * 60; i += 256) {
    int h = i / 60, f = i - h * 60;
    ewL[h * 61 + f] = enc_w[i];
  }
  __syncthreads();
  for (int i = tid; i < 32 * 60; i += 256) {
    int r = i / 60, f = i - r * 60;
    nrm[r * 61 + f] = (inps[(size_t)(r0 + r) * 64 + f] - muL[f]) * ivL[f];
  }
  __syncthreads();
  for (int i = tid; i < 32 * 128; i += 256) {
    int r = i >> 7, h = i & 127;
    float a = ebL[h];
    #pragma unroll 4
    for (int f = 0; f < 60; ++f) a += nrm[r * 61 + f] * ewL[h * 61 + f];
    a = a >= 0.f ? a : 0.01f * a;
    sab[(size_t)(r0 + r) * 128 + h] = f2b(a);
  }
}

// ---------------------------------------------------------------------------
// attention combine: per-b softmax over other agents + emb = [sa | other] (bf16)
__global__ __launch_bounds__(128) void attn_combine(
    const u16* __restrict__ qb, const u16* __restrict__ keysb,
    const u16* __restrict__ valsb, const u16* __restrict__ sab,
    u16* __restrict__ emb) {
  __shared__ float qL[3][128], kL[3][128], vL[3][128];
  __shared__ float lg[3][8][3], wgt[3][8][3];
  int b = blockIdx.x, t = threadIdx.x;
  #pragma unroll
  for (int o = 0; o < 3; ++o) {
    size_t base = (size_t)(o * 4096 + b) * 128 + t;
    qL[o][t] = b2f(qb[base]);
    kL[o][t] = b2f(keysb[base]);
    vL[o][t] = b2f(valsb[base]);
  }
  __syncthreads();
  if (t < 72) {
    int g = t / 24, n = (t / 3) % 8, o = t % 3;
    float a = 0.f;
    #pragma unroll
    for (int d = 0; d < 16; ++d) a += qL[g][n * 16 + d] * kL[o][n * 16 + d];
    lg[g][n][o] = (o == g) ? -1e30f : a * 0.25f;
  }
  __syncthreads();
  if (t < 24) {
    int g = t / 8, n = t % 8;
    float m = fmaxf(fmaxf(lg[g][n][0], lg[g][n][1]), lg[g][n][2]);
    float e0 = expf(lg[g][n][0] - m), e1 = expf(lg[g][n][1] - m),
          e2 = expf(lg[g][n][2] - m);
    float inv = 1.f / (e0 + e1 + e2);
    wgt[g][n][0] = e0 * inv; wgt[g][n][1] = e1 * inv; wgt[g][n][2] = e2 * inv;
  }
  __syncthreads();
  int n = t >> 4, d = t & 15;
  #pragma unroll
  for (int g = 0; g < 3; ++g) {
    float o_ = wgt[g][n][0] * vL[0][n * 16 + d] +
               wgt[g][n][1] * vL[1][n * 16 + d] +
               wgt[g][n][2] * vL[2][n * 16 + d];
    size_t rbase = (size_t)(g * 4096 + b) * 256;
    emb[rbase + 128 + t] = f2b(o_);
    emb[rbase + t] = sab[(size_t)(g * 4096 + b) * 128 + t];
  }
}

// ---------------------------------------------------------------------------
// final layer: out[row] = t2 . w3 + b3 for both heads. One wave per row.
__global__ __launch_bounds__(256) void final_dot(
    const u16* __restrict__ t2a, const u16* __restrict__ t2b,
    const float* __restrict__ w3a, const float* __restrict__ b3a,
    const float* __restrict__ w3b, const float* __restrict__ b3b,
    float* __restrict__ out) {
  int wv = threadIdx.x >> 6, lane = threadIdx.x & 63;
  int row = blockIdx.x * 4 + wv;
  float sa_ = 0.f, sb_ = 0.f;
  #pragma unroll
  for (int e = 0; e < 4; ++e) {
    int c = lane * 4 + e;
    sa_ += b2f(t2a[(size_t)row * 256 + c]) * w3a[c];
    sb_ += b2f(t2b[(size_t)row * 256 + c]) * w3b[c];
  }
  #pragma unroll
  for (int off = 32; off; off >>= 1) {
    sa_ += __shfl_down(sa_, off);
    sb_ += __shfl_down(sb_, off);
  }
  if (lane == 0) {
    out[row] = sa_ + b3a[0];
    out[12288 + row] = sb_ + b3b[0];
  }
}

// ---------------------------------------------------------------------------
extern "C" void kernel_launch(void* const* d_in, const int* in_sizes, int n_in,
                              void* d_out, int out_size, void* d_ws,
                              size_t ws_size, hipStream_t stream) {
  const float* obs  = (const float*)d_in[0];
  const float* acts = (const float*)d_in[1];
  const float* scan = (const float*)d_in[2];
  const float* cw1  = (const float*)d_in[3];
  const float* cb1  = (const float*)d_in[4];
  const float* cw2  = (const float*)d_in[5];
  const float* cb2  = (const float*)d_in[6];
  const float* fw1  = (const float*)d_in[7];
  const float* fb1  = (const float*)d_in[8];
  const float* fw2  = (const float*)d_in[9];
  const float* fb2  = (const float*)d_in[10];
  const float* encw = (const float*)d_in[11];
  const float* encb = (const float*)d_in[12];
  const float* Wk   = (const float*)d_in[13];
  const float* Wv   = (const float*)d_in[14];
  const float* bv   = (const float*)d_in[15];
  const float* Wq   = (const float*)d_in[16];
  const float* q1w1 = (const float*)d_in[17];
  const float* q1b1 = (const float*)d_in[18];
  const float* q1w2 = (const float*)d_in[19];
  const float* q1b2 = (const float*)d_in[20];
  const float* q1w3 = (const float*)d_in[21];
  const float* q1b3 = (const float*)d_in[22];
  const float* q2w1 = (const float*)d_in[23];
  const float* q2b1 = (const float*)d_in[24];
  const float* q2w2 = (const float*)d_in[25];
  const float* q2b2 = (const float*)d_in[26];
  const float* q2w3 = (const float*)d_in[27];
  const float* q2b3 = (const float*)d_in[28];
  float* out = (float*)d_out;
  char* ws = (char*)d_ws;
  if (ws_size < 166009856u) return;  // need ~158 MB scratch

  // persistent region
  u16*   x     = (u16*)(ws + 0);           // slab: 6144*8000 bf16 = 98,304,000 B
  u16*   w1b   = (u16*)(ws + 98304000);    // 256*8000 bf16
  float* hpart = (float*)(ws + 102400000); // 5 * 12288*256 fp32 (split-K partials)
  float* stats = (float*)(ws + 165314560); // 128 sums + 128 sumsq (uses 60/60)
  u16*   wkb   = (u16*)(ws + 165315584);
  u16*   wvb   = (u16*)(ws + 165348352);
  u16*   wqb   = (u16*)(ws + 165381120);
  u16*   m1a   = (u16*)(ws + 165479424);
  u16*   m2a   = (u16*)(ws + 165610496);
  u16*   m1b   = (u16*)(ws + 165741568);
  u16*   m2b   = (u16*)(ws + 165872640);
  u16*   w2g   = (u16*)(ws + 166003712);   // 32*96 bf16 conv2 weights
  // region aliasing x (x is dead after the last fc1 GEMM)
  float* inps  = (float*)(ws + 0);         // 12288*64 fp32
  u16*   sab   = (u16*)(ws + 3145728);
  u16*   keysb = (u16*)(ws + 6291456);
  u16*   valsb = (u16*)(ws + 9437184);
  u16*   qb    = (u16*)(ws + 12582912);
  u16*   embb  = (u16*)(ws + 15728640);    // 12288*256 bf16
  u16*   t1a   = (u16*)(ws + 22020096);
  u16*   t2a   = (u16*)(ws + 28311552);
  u16*   t1b   = (u16*)(ws + 34603008);
  u16*   t2b   = (u16*)(ws + 40894464);

  w1_perm<<<256, 256, 0, stream>>>(fw1, w1b);
  CvtArgs ca;
  ca.src[0] = Wk;  ca.src[1] = Wv;  ca.src[2] = Wq;  ca.src[3] = q1w1;
  ca.src[4] = q1w2; ca.src[5] = q2w1; ca.src[6] = q2w2; ca.src[7] = cw2;
  ca.dst[0] = wkb; ca.dst[1] = wvb; ca.dst[2] = wqb; ca.dst[3] = m1a;
  ca.dst[4] = m2a; ca.dst[5] = m1b; ca.dst[6] = m2b; ca.dst[7] = w2g;
  const int sz[8] = {16384, 16384, 49152, 65536, 65536, 65536, 65536, 3072};
  int cum = 0;
  ca.cum[0] = 0;
  for (int i = 0; i < 8; ++i) { cum += sz[i]; ca.cum[i + 1] = cum; }
  f2b_multi<<<(cum + 255) / 256, 256, 0, stream>>>(ca, stats);

  // conv + fc1 in 2 row slabs (x buffer holds one slab at a time)
  for (int s = 0; s < 2; ++s) {
    conv_fused<<<6144, 256, 0, stream>>>(scan, cw1, cb1, w2g, cb2, x, s * 6144);
    gemm_bt<0><<<dim3(2, 48, 5), 256, 0, stream>>>(
        x, 8000, w1b, nullptr, hpart + (size_t)s * 6144 * 256, nullptr, 256,
        50, 0, (size_t)12288 * 256);
  }
  fc2_stats<<<384, 256, 0, stream>>>(hpart, fb1, fw2, fb2, obs, acts, inps, stats);
  enc_kernel<<<384, 256, 0, stream>>>(inps, stats, encw, encb, sab);
  gemm_bt<3><<<dim3(1, 96, 1), 256, 0, stream>>>(sab, 128, wkb, nullptr, nullptr,
                                                 keysb, 128, 4, 0, 0);
  gemm_bt<2><<<dim3(1, 96, 1), 256, 0, stream>>>(sab, 128, wvb, bv, nullptr,
                                                 valsb, 128, 4, 0, 0);
  gemm_bt<3><<<dim3(1, 96, 1), 256, 0, stream>>>(sab, 128, wqb, nullptr, nullptr,
                                                 qb, 128, 4, 16384, 0);
  attn_combine<<<4096, 128, 0, stream>>>(qb, keysb, valsb, sab, embb);
  gemm_bt<1><<<dim3(2, 96, 1), 256, 0, stream>>>(embb, 256, m1a, q1b1, nullptr,
                                                 t1a, 256, 8, 0, 0);
  gemm_bt<1><<<dim3(2, 96, 1), 256, 0, stream>>>(t1a, 256, m2a, q1b2, nullptr,
                                                 t2a, 256, 8, 0, 0);
  gemm_bt<1><<<dim3(2, 96, 1), 256, 0, stream>>>(embb, 256, m1b, q2b1, nullptr,
                                                 t1b, 256, 8, 0, 0);
  gemm_bt<1><<<dim3(2, 96, 1), 256, 0, stream>>>(t1b, 256, m2b, q2b2, nullptr,
                                                 t2b, 256, 8, 0, 0);
  final_dot<<<3072, 256, 0, stream>>>(t2a, t2b, q1w3, q1b3, q2w3, q2b3, out);
}

// Round 3
// 379.891 us; speedup vs baseline: 1.1692x; 1.0912x over previous
//
#include <hip/hip_runtime.h>
#include <hip/hip_bf16.h>
#include <cstdint>
#include <cstddef>

typedef unsigned short u16;
typedef __attribute__((ext_vector_type(8))) __bf16 bf16x8;
typedef __attribute__((ext_vector_type(4))) float f32x4;

__device__ __forceinline__ u16 f2b(float f) {
  __hip_bfloat16 h = __float2bfloat16(f);
  return *reinterpret_cast<u16*>(&h);
}
__device__ __forceinline__ uint32_t pk2(float a, float b) {
  __hip_bfloat162 h = __float22bfloat162_rn(make_float2(a, b));
  return *reinterpret_cast<uint32_t*>(&h);
}
__device__ __forceinline__ float b2f(u16 u) {
  union { float f; uint32_t i; } x; x.i = ((uint32_t)u) << 16; return x.f;
}
__device__ __forceinline__ f32x4 mfma16(bf16x8 a, bf16x8 b, f32x4 c) {
  return __builtin_amdgcn_mfma_f32_16x16x32_bf16(a, b, c, 0, 0, 0);
}
__device__ __forceinline__ void async16(const void* g, void* l) {
  __builtin_amdgcn_global_load_lds((const __attribute__((address_space(1))) uint32_t*)g,
                                   (__attribute__((address_space(3))) uint32_t*)l, 16, 0, 0);
}

// ---------------------------------------------------------------------------
// Weight conversion: fc_w1 (256x8000) permuted k: out[j][t*32+c2] = w[j][c2*250+t]
__global__ __launch_bounds__(256) void w1_perm(const float* __restrict__ w,
                                               u16* __restrict__ o) {
  __shared__ float L[8000];
  int j = blockIdx.x, tid = threadIdx.x;
  for (int i = tid; i < 8000; i += 256) L[i] = w[(size_t)j * 8000 + i];
  __syncthreads();
  for (int i = tid; i < 8000; i += 256) {
    int tt = i >> 5, c2 = i & 31;
    o[(size_t)j * 8000 + i] = f2b(L[c2 * 250 + tt]);
  }
}

struct CvtArgs {
  const float* src[8];
  u16* dst[8];
  int cum[9];
};
// segments 0..6: straight f32->bf16; segment 7: conv_w2 permute ->
//   w2g[c2][kk*32+c1] = bf16(cw2[(c2*32+c1)*3+kk])
__global__ __launch_bounds__(256) void f2b_multi(CvtArgs a, float* stats) {
  int i = blockIdx.x * 256 + threadIdx.x;
  if (blockIdx.x == 0 && threadIdx.x < 128) stats[threadIdx.x] = 0.f;
  int seg = 0;
  #pragma unroll
  for (int s = 1; s < 8; ++s) if (i >= a.cum[s]) seg = s;
  if (i < a.cum[8]) {
    int off = i - a.cum[seg];
    if (seg == 7) {
      int c2 = off / 96, rem = off - c2 * 96, kk = rem >> 5, c1 = rem & 31;
      a.dst[7][off] = f2b(a.src[7][(c2 * 32 + c1) * 3 + kk]);
    } else {
      a.dst[seg][off] = f2b(a.src[seg][off]);
    }
  }
}

// ---------------------------------------------------------------------------
// Fused conv1 (fp32, register-blocked) + conv2 (bf16 MFMA) per scan row.
// x out layout: x[row][t*32 + c2]  (matches permuted fc_w1)
__global__ __launch_bounds__(256) void conv_fused(
    const float* __restrict__ scan, const float* __restrict__ cw1,
    const float* __restrict__ cb1, const u16* __restrict__ w2g,
    const float* __restrict__ cb2, u16* __restrict__ x, int row0) {
  __shared__ float s[260];
  __shared__ __align__(16) u16 h1T[258 * 40];  // [p][c1], stride 40 (bank-safe)
  int tid = threadIdx.x;
  int lrow = blockIdx.x;
  int lane = tid & 63, wv = tid >> 6;
  int l15 = lane & 15, quad = lane >> 4;
  s[tid] = scan[(size_t)(row0 + lrow) * 256 + tid];
  if (tid < 4) s[256 + tid] = 0.f;
  if (tid < 240) h1T[252 * 40 + tid] = 0;  // zero rows 252..257
  // preload conv2 weight fragments (A operand, m=c2): 6 KB, L1-hot
  bf16x8 wfrag[2][3];
  #pragma unroll
  for (int i = 0; i < 2; ++i)
    #pragma unroll
    for (int kk = 0; kk < 3; ++kk)
      wfrag[i][kk] = *(const bf16x8*)&w2g[(i * 16 + l15) * 96 + kk * 32 + quad * 8];
  float bias[2][4];
  #pragma unroll
  for (int i = 0; i < 2; ++i)
    #pragma unroll
    for (int r = 0; r < 4; ++r) bias[i][r] = cb2[i * 16 + quad * 4 + r];
  __syncthreads();
  {  // conv1: thread = (pr = tid>>4: p in [pr*16, pr*16+16)) x (cpair = tid&15)
    int cpair = tid & 15, pr = tid >> 4;
    int c0 = cpair * 2;
    float wA[5], wB[5];
    #pragma unroll
    for (int k = 0; k < 5; ++k) { wA[k] = cw1[c0 * 5 + k]; wB[k] = cw1[c0 * 5 + 5 + k]; }
    float bA = cb1[c0], bB = cb1[c0 + 1];
    float sv[20];
    int p0 = pr * 16;
    #pragma unroll
    for (int j = 0; j < 5; ++j) {
      f32x4 v = *(const f32x4*)&s[p0 + 4 * j];
      sv[4 * j] = v[0]; sv[4 * j + 1] = v[1]; sv[4 * j + 2] = v[2]; sv[4 * j + 3] = v[3];
    }
    #pragma unroll
    for (int ii = 0; ii < 16; ++ii) {
      float va = bA, vb = bB;
      #pragma unroll
      for (int k = 0; k < 5; ++k) {
        va += sv[ii + k] * wA[k];
        vb += sv[ii + k] * wB[k];
      }
      int p = p0 + ii;
      if (p < 252) {
        *(uint32_t*)&h1T[p * 40 + c0] = pk2(fmaxf(va, 0.f), fmaxf(vb, 0.f));
      }
    }
  }
  __syncthreads();
  // conv2 MFMA: D[c2][t] with A=w2 (m=c2), B=h1 (n=t)
  f32x4 zero = {0.f, 0.f, 0.f, 0.f};
  f32x4 acc[4][2];
  #pragma unroll
  for (int jj = 0; jj < 4; ++jj) { acc[jj][0] = zero; acc[jj][1] = zero; }
  #pragma unroll
  for (int kk = 0; kk < 3; ++kk) {
    #pragma unroll
    for (int jj = 0; jj < 4; ++jj) {
      int t = (wv * 4 + jj) * 16 + l15 + kk;
      bf16x8 h = *(const bf16x8*)&h1T[t * 40 + quad * 8];
      acc[jj][0] = mfma16(wfrag[0][kk], h, acc[jj][0]);
      acc[jj][1] = mfma16(wfrag[1][kk], h, acc[jj][1]);
    }
  }
  __syncthreads();  // h1T reads done; reuse buffer as xT[t][c2] stride 40
  #pragma unroll
  for (int jj = 0; jj < 4; ++jj) {
    int t = (wv * 4 + jj) * 16 + l15;
    if (t < 250) {
      #pragma unroll
      for (int i = 0; i < 2; ++i) {
        float v0 = fmaxf(acc[jj][i][0] + bias[i][0], 0.f);
        float v1 = fmaxf(acc[jj][i][1] + bias[i][1], 0.f);
        float v2 = fmaxf(acc[jj][i][2] + bias[i][2], 0.f);
        float v3 = fmaxf(acc[jj][i][3] + bias[i][3], 0.f);
        uint2 pr2; pr2.x = pk2(v0, v1); pr2.y = pk2(v2, v3);
        *(uint2*)&h1T[t * 40 + i * 16 + quad * 4] = pr2;
      }
    }
  }
  __syncthreads();
  u16* xr = x + (size_t)lrow * 8000;
  #pragma unroll
  for (int it = 0; it < 4; ++it) {
    int e0 = (it * 256 + tid) * 8;
    if (e0 < 8000) {
      int t = e0 >> 5, c8 = (e0 >> 3) & 3;
      bf16x8 v = *(const bf16x8*)&h1T[t * 40 + c8 * 8];
      *(bf16x8*)&xr[e0] = v;
    }
  }
}

// ---------------------------------------------------------------------------
// Generic NT bf16 MFMA GEMM, BK=64 stages, double-buffered LDS with depth-1
// async prefetch, XOR-swizzled chunks (conflict-free ds_read_b128).
// out[m][n] = act(sum_k A[m][k]*W[n][k] + bias[n])
// MODE 0: raw fp32 store (split-K partials). MODE 1: +bias relu bf16.
// MODE 2: +bias leaky bf16. MODE 3: bf16 raw.
// nst = number of 64-wide K stages; kbase = blockIdx.z * nst * 64.
template <int MODE>
__global__ __launch_bounds__(256) void gemm_bt(
    const u16* __restrict__ A, int lda, const u16* __restrict__ W,
    const float* __restrict__ bias, float* __restrict__ outF,
    u16* __restrict__ outB, int ldo, int nst, int wq_sel, size_t out_zoff) {
  __shared__ __align__(16) u16 As[2][128 * 64];
  __shared__ __align__(16) u16 Bs[2][128 * 64];
  int tid = threadIdx.x;
  int m0 = blockIdx.y * 128, n0 = blockIdx.x * 128;
  if (wq_sel) W += (size_t)(blockIdx.y >> 5) * wq_sel;
  int kbase = blockIdx.z * nst * 64;
  if (MODE == 0) outF += (size_t)blockIdx.z * out_zoff;
  const u16* Ap = A + (size_t)m0 * lda + kbase;
  const u16* Wp = W + (size_t)n0 * lda + kbase;
  int lane = tid & 63, wv = tid >> 6;
  int l15 = lane & 15, quad = lane >> 4;
  int wm = (wv >> 1) * 64, wn = (wv & 1) * 64;
  f32x4 zero = {0.f, 0.f, 0.f, 0.f};
  f32x4 acc[4][4];
  #pragma unroll
  for (int i = 0; i < 4; ++i)
    #pragma unroll
    for (int j = 0; j < 4; ++j) acc[i][j] = zero;

  // per-thread staging chunk descriptors (4 chunks per matrix per stage)
  int srow[4], soff[4], sdst[4];
  #pragma unroll
  for (int it = 0; it < 4; ++it) {
    int c = it * 256 + tid;          // chunk id 0..1023
    int row = c >> 3, slot = c & 7;  // 128 rows x 8 chunks of 16B
    srow[it] = row;
    soff[it] = ((slot ^ (row & 7)) * 8);  // swizzled source k-chunk (u16 units)
    sdst[it] = c * 8;                     // dest (u16 units): base + lane*16B
  }
  int rslot[2];  // reader slot per substep: (s*4+quad) ^ (l15&7), in u16 units
  rslot[0] = ((quad ^ (l15 & 7)) * 8);
  rslot[1] = (((4 + quad) ^ (l15 & 7)) * 8);

  #pragma unroll 1
  for (int st = 0; st < nst; ++st) {
    if (st == 0) {
      #pragma unroll
      for (int it = 0; it < 4; ++it) {
        async16(Ap + (size_t)srow[it] * lda + soff[it], &As[0][sdst[it]]);
        async16(Wp + (size_t)srow[it] * lda + soff[it], &Bs[0][sdst[it]]);
      }
    }
    __syncthreads();  // vmcnt(0) drain: buf[st&1] ready
    if (st + 1 < nst) {
      const u16* An = Ap + (st + 1) * 64;
      const u16* Wn = Wp + (st + 1) * 64;
      u16* Ad = &As[(st + 1) & 1][0];
      u16* Bd = &Bs[(st + 1) & 1][0];
      #pragma unroll
      for (int it = 0; it < 4; ++it) {
        async16(An + (size_t)srow[it] * lda + soff[it], Ad + sdst[it]);
        async16(Wn + (size_t)srow[it] * lda + soff[it], Bd + sdst[it]);
      }
    }
    const u16* Ab = &As[st & 1][0];
    const u16* Bb = &Bs[st & 1][0];
    #pragma unroll
    for (int s = 0; s < 2; ++s) {
      bf16x8 af[4], bfr[4];
      #pragma unroll
      for (int i = 0; i < 4; ++i)
        af[i] = *(const bf16x8*)&Ab[(wm + i * 16 + l15) * 64 + rslot[s]];
      #pragma unroll
      for (int j = 0; j < 4; ++j)
        bfr[j] = *(const bf16x8*)&Bb[(wn + j * 16 + l15) * 64 + rslot[s]];
      #pragma unroll
      for (int i = 0; i < 4; ++i)
        #pragma unroll
        for (int j = 0; j < 4; ++j) acc[i][j] = mfma16(af[i], bfr[j], acc[i][j]);
    }
  }
  #pragma unroll
  for (int i = 0; i < 4; ++i) {
    int mb = m0 + wm + i * 16 + quad * 4;
    #pragma unroll
    for (int j = 0; j < 4; ++j) {
      int n = n0 + wn + j * 16 + l15;
      float bv_ = (MODE == 1 || MODE == 2) ? bias[n] : 0.f;
      #pragma unroll
      for (int r = 0; r < 4; ++r) {
        float v = acc[i][j][r];
        if (MODE == 0) {
          outF[(size_t)(mb + r) * ldo + n] = v;
        } else {
          v += bv_;
          if (MODE == 1) v = fmaxf(v, 0.f);
          if (MODE == 2) v = v >= 0.f ? v : 0.01f * v;
          outB[(size_t)(mb + r) * ldo + n] = f2b(v);
        }
      }
    }
  }
}

// ---------------------------------------------------------------------------
// fc2 (relu(sum hparts + b1) @ w2^T + b2) + build inps rows + batch-stat partials
__global__ __launch_bounds__(256) void fc2_stats(
    const float* __restrict__ hparts, const float* __restrict__ b1,
    const float* __restrict__ w2, const float* __restrict__ b2,
    const float* __restrict__ obs, const float* __restrict__ acts,
    float* __restrict__ inps, float* __restrict__ stats) {
  __shared__ float hL[32 * 260];
  __shared__ float w2L[10 * 260];
  __shared__ float b1L[256];
  __shared__ float ipL[32 * 61];
  int tid = threadIdx.x, r0 = blockIdx.x * 32;
  b1L[tid] = b1[tid];
  for (int i = tid; i < 2560; i += 256) w2L[(i >> 8) * 260 + (i & 255)] = w2[i];
  for (int i = tid; i < 32 * 48; i += 256) {
    int r = i / 48, f = i - r * 48;
    ipL[r * 61 + f] = obs[(size_t)(r0 + r) * 48 + f];
  }
  if (tid < 64) {
    int r = tid >> 1, f = tid & 1;
    ipL[r * 61 + 48 + f] = acts[(size_t)(r0 + r) * 2 + f];
  }
  __syncthreads();
  const size_t HS = (size_t)12288 * 256;
  for (int i = tid; i < 32 * 256; i += 256) {
    int r = i >> 8, c = i & 255;
    size_t g = (size_t)(r0 + r) * 256 + c;
    float v = b1L[c] + hparts[g] + hparts[g + HS] + hparts[g + 2 * HS] +
              hparts[g + 3 * HS] + hparts[g + 4 * HS];
    hL[r * 260 + c] = fmaxf(v, 0.f);
  }
  __syncthreads();
  {
    int r = tid >> 3, ob = tid & 7;
    for (int o = ob; o < 10; o += 8) {
      float a = 0.f;
      #pragma unroll 8
      for (int c = 0; c < 256; ++c) a += hL[r * 260 + c] * w2L[o * 260 + c];
      ipL[r * 61 + 50 + o] = a + b2[o];
    }
  }
  __syncthreads();
  for (int i = tid; i < 32 * 60; i += 256) {
    int r = i / 60, f = i - r * 60;
    inps[(size_t)(r0 + r) * 64 + f] = ipL[r * 61 + f];
  }
  if (tid < 60) {
    float s = 0.f, s2 = 0.f;
    for (int r = 0; r < 32; ++r) {
      float v = ipL[r * 61 + tid];
      s += v; s2 += v * v;
    }
    atomicAdd(&stats[tid], s);
    atomicAdd(&stats[64 + tid], s2);
  }
}

// ---------------------------------------------------------------------------
// normalize + enc (60->128) + leaky -> sa (bf16)
__global__ __launch_bounds__(256) void enc_kernel(
    const float* __restrict__ inps, const float* __restrict__ stats,
    const float* __restrict__ enc_w, const float* __restrict__ enc_b,
    u16* __restrict__ sab) {
  __shared__ float ewL[128 * 61];
  __shared__ float nrm[32 * 61];
  __shared__ float ebL[128];
  __shared__ float muL[60], ivL[60];
  int tid = threadIdx.x, r0 = blockIdx.x * 32;
  if (tid < 128) ebL[tid] = enc_b[tid];
  if (tid < 60) {
    float s = stats[tid], s2 = stats[64 + tid];
    float mu = s * (1.f / 12288.f);
    float var = s2 * (1.f / 12288.f) - mu * mu;
    muL[tid] = mu;
    ivL[tid] = rsqrtf(var + 1e-5f);
  }
  for (int i = tid; i < 128 * 60; i += 256) {
    int h = i / 60, f = i - h * 60;
    ewL[h * 61 + f] = enc_w[i];
  }
  __syncthreads();
  for (int i = tid; i < 32 * 60; i += 256) {
    int r = i / 60, f = i - r * 60;
    nrm[r * 61 + f] = (inps[(size_t)(r0 + r) * 64 + f] - muL[f]) * ivL[f];
  }
  __syncthreads();
  for (int i = tid; i < 32 * 128; i += 256) {
    int r = i >> 7, h = i & 127;
    float a = ebL[h];
    #pragma unroll 4
    for (int f = 0; f < 60; ++f) a += nrm[r * 61 + f] * ewL[h * 61 + f];
    a = a >= 0.f ? a : 0.01f * a;
    sab[(size_t)(r0 + r) * 128 + h] = f2b(a);
  }
}

// ---------------------------------------------------------------------------
// attention combine: per-b softmax over other agents + emb = [sa | other] (bf16)
__global__ __launch_bounds__(128) void attn_combine(
    const u16* __restrict__ qb, const u16* __restrict__ keysb,
    const u16* __restrict__ valsb, const u16* __restrict__ sab,
    u16* __restrict__ emb) {
  __shared__ float qL[3][128], kL[3][128], vL[3][128];
  __shared__ float lg[3][8][3], wgt[3][8][3];
  int b = blockIdx.x, t = threadIdx.x;
  #pragma unroll
  for (int o = 0; o < 3; ++o) {
    size_t base = (size_t)(o * 4096 + b) * 128 + t;
    qL[o][t] = b2f(qb[base]);
    kL[o][t] = b2f(keysb[base]);
    vL[o][t] = b2f(valsb[base]);
  }
  __syncthreads();
  if (t < 72) {
    int g = t / 24, n = (t / 3) % 8, o = t % 3;
    float a = 0.f;
    #pragma unroll
    for (int d = 0; d < 16; ++d) a += qL[g][n * 16 + d] * kL[o][n * 16 + d];
    lg[g][n][o] = (o == g) ? -1e30f : a * 0.25f;
  }
  __syncthreads();
  if (t < 24) {
    int g = t / 8, n = t % 8;
    float m = fmaxf(fmaxf(lg[g][n][0], lg[g][n][1]), lg[g][n][2]);
    float e0 = expf(lg[g][n][0] - m), e1 = expf(lg[g][n][1] - m),
          e2 = expf(lg[g][n][2] - m);
    float inv = 1.f / (e0 + e1 + e2);
    wgt[g][n][0] = e0 * inv; wgt[g][n][1] = e1 * inv; wgt[g][n][2] = e2 * inv;
  }
  __syncthreads();
  int n = t >> 4, d = t & 15;
  #pragma unroll
  for (int g = 0; g < 3; ++g) {
    float o_ = wgt[g][n][0] * vL[0][n * 16 + d] +
               wgt[g][n][1] * vL[1][n * 16 + d] +
               wgt[g][n][2] * vL[2][n * 16 + d];
    size_t rbase = (size_t)(g * 4096 + b) * 256;
    emb[rbase + 128 + t] = f2b(o_);
    emb[rbase + t] = sab[(size_t)(g * 4096 + b) * 128 + t];
  }
}

// ---------------------------------------------------------------------------
// final layer: out[row] = t2 . w3 + b3 for both heads. One wave per row.
__global__ __launch_bounds__(256) void final_dot(
    const u16* __restrict__ t2a, const u16* __restrict__ t2b,
    const float* __restrict__ w3a, const float* __restrict__ b3a,
    const float* __restrict__ w3b, const float* __restrict__ b3b,
    float* __restrict__ out) {
  int wv = threadIdx.x >> 6, lane = threadIdx.x & 63;
  int row = blockIdx.x * 4 + wv;
  float sa_ = 0.f, sb_ = 0.f;
  #pragma unroll
  for (int e = 0; e < 4; ++e) {
    int c = lane * 4 + e;
    sa_ += b2f(t2a[(size_t)row * 256 + c]) * w3a[c];
    sb_ += b2f(t2b[(size_t)row * 256 + c]) * w3b[c];
  }
  #pragma unroll
  for (int off = 32; off; off >>= 1) {
    sa_ += __shfl_down(sa_, off);
    sb_ += __shfl_down(sb_, off);
  }
  if (lane == 0) {
    out[row] = sa_ + b3a[0];
    out[12288 + row] = sb_ + b3b[0];
  }
}

// ---------------------------------------------------------------------------
extern "C" void kernel_launch(void* const* d_in, const int* in_sizes, int n_in,
                              void* d_out, int out_size, void* d_ws,
                              size_t ws_size, hipStream_t stream) {
  const float* obs  = (const float*)d_in[0];
  const float* acts = (const float*)d_in[1];
  const float* scan = (const float*)d_in[2];
  const float* cw1  = (const float*)d_in[3];
  const float* cb1  = (const float*)d_in[4];
  const float* cw2  = (const float*)d_in[5];
  const float* cb2  = (const float*)d_in[6];
  const float* fw1  = (const float*)d_in[7];
  const float* fb1  = (const float*)d_in[8];
  const float* fw2  = (const float*)d_in[9];
  const float* fb2  = (const float*)d_in[10];
  const float* encw = (const float*)d_in[11];
  const float* encb = (const float*)d_in[12];
  const float* Wk   = (const float*)d_in[13];
  const float* Wv   = (const float*)d_in[14];
  const float* bv   = (const float*)d_in[15];
  const float* Wq   = (const float*)d_in[16];
  const float* q1w1 = (const float*)d_in[17];
  const float* q1b1 = (const float*)d_in[18];
  const float* q1w2 = (const float*)d_in[19];
  const float* q1b2 = (const float*)d_in[20];
  const float* q1w3 = (const float*)d_in[21];
  const float* q1b3 = (const float*)d_in[22];
  const float* q2w1 = (const float*)d_in[23];
  const float* q2b1 = (const float*)d_in[24];
  const float* q2w2 = (const float*)d_in[25];
  const float* q2b2 = (const float*)d_in[26];
  const float* q2w3 = (const float*)d_in[27];
  const float* q2b3 = (const float*)d_in[28];
  float* out = (float*)d_out;
  char* ws = (char*)d_ws;
  if (ws_size < 166009856u) return;  // need ~158 MB scratch

  // persistent region
  u16*   x     = (u16*)(ws + 0);           // slab: 6144*8000 bf16 = 98,304,000 B
  u16*   w1b   = (u16*)(ws + 98304000);    // 256*8000 bf16
  float* hpart = (float*)(ws + 102400000); // 5 * 12288*256 fp32 (split-K partials)
  float* stats = (float*)(ws + 165314560); // 128 sums + 128 sumsq (uses 60/60)
  u16*   wkb   = (u16*)(ws + 165315584);
  u16*   wvb   = (u16*)(ws + 165348352);
  u16*   wqb   = (u16*)(ws + 165381120);
  u16*   m1a   = (u16*)(ws + 165479424);
  u16*   m2a   = (u16*)(ws + 165610496);
  u16*   m1b   = (u16*)(ws + 165741568);
  u16*   m2b   = (u16*)(ws + 165872640);
  u16*   w2g   = (u16*)(ws + 166003712);   // 32*96 bf16 conv2 weights
  // region aliasing x (x is dead after the last fc1 GEMM)
  float* inps  = (float*)(ws + 0);         // 12288*64 fp32
  u16*   sab   = (u16*)(ws + 3145728);
  u16*   keysb = (u16*)(ws + 6291456);
  u16*   valsb = (u16*)(ws + 9437184);
  u16*   qb    = (u16*)(ws + 12582912);
  u16*   embb  = (u16*)(ws + 15728640);    // 12288*256 bf16
  u16*   t1a   = (u16*)(ws + 22020096);
  u16*   t2a   = (u16*)(ws + 28311552);
  u16*   t1b   = (u16*)(ws + 34603008);
  u16*   t2b   = (u16*)(ws + 40894464);

  w1_perm<<<256, 256, 0, stream>>>(fw1, w1b);
  CvtArgs ca;
  ca.src[0] = Wk;  ca.src[1] = Wv;  ca.src[2] = Wq;  ca.src[3] = q1w1;
  ca.src[4] = q1w2; ca.src[5] = q2w1; ca.src[6] = q2w2; ca.src[7] = cw2;
  ca.dst[0] = wkb; ca.dst[1] = wvb; ca.dst[2] = wqb; ca.dst[3] = m1a;
  ca.dst[4] = m2a; ca.dst[5] = m1b; ca.dst[6] = m2b; ca.dst[7] = w2g;
  const int sz[8] = {16384, 16384, 49152, 65536, 65536, 65536, 65536, 3072};
  int cum = 0;
  ca.cum[0] = 0;
  for (int i = 0; i < 8; ++i) { cum += sz[i]; ca.cum[i + 1] = cum; }
  f2b_multi<<<(cum + 255) / 256, 256, 0, stream>>>(ca, stats);

  // conv + fc1 in 2 row slabs (x buffer holds one slab at a time)
  for (int s = 0; s < 2; ++s) {
    conv_fused<<<6144, 256, 0, stream>>>(scan, cw1, cb1, w2g, cb2, x, s * 6144);
    gemm_bt<0><<<dim3(2, 48, 5), 256, 0, stream>>>(
        x, 8000, w1b, nullptr, hpart + (size_t)s * 6144 * 256, nullptr, 256,
        25, 0, (size_t)12288 * 256);
  }
  fc2_stats<<<384, 256, 0, stream>>>(hpart, fb1, fw2, fb2, obs, acts, inps, stats);
  enc_kernel<<<384, 256, 0, stream>>>(inps, stats, encw, encb, sab);
  gemm_bt<3><<<dim3(1, 96, 1), 256, 0, stream>>>(sab, 128, wkb, nullptr, nullptr,
                                                 keysb, 128, 2, 0, 0);
  gemm_bt<2><<<dim3(1, 96, 1), 256, 0, stream>>>(sab, 128, wvb, bv, nullptr,
                                                 valsb, 128, 2, 0, 0);
  gemm_bt<3><<<dim3(1, 96, 1), 256, 0, stream>>>(sab, 128, wqb, nullptr, nullptr,
                                                 qb, 128, 2, 16384, 0);
  attn_combine<<<4096, 128, 0, stream>>>(qb, keysb, valsb, sab, embb);
  gemm_bt<1><<<dim3(2, 96, 1), 256, 0, stream>>>(embb, 256, m1a, q1b1, nullptr,
                                                 t1a, 256, 4, 0, 0);
  gemm_bt<1><<<dim3(2, 96, 1), 256, 0, stream>>>(t1a, 256, m2a, q1b2, nullptr,
                                                 t2a, 256, 4, 0, 0);
  gemm_bt<1><<<dim3(2, 96, 1), 256, 0, stream>>>(embb, 256, m1b, q2b1, nullptr,
                                                 t1b, 256, 4, 0, 0);
  gemm_bt<1><<<dim3(2, 96, 1), 256, 0, stream>>>(t1b, 256, m2b, q2b2, nullptr,
                                                 t2b, 256, 4, 0, 0);
  final_dot<<<3072, 256, 0, stream>>>(t2a, t2b, q1w3, q1b3, q2w3, q2b3, out);
}

// Round 5
// 358.236 us; speedup vs baseline: 1.2399x; 1.0604x over previous
//
#include <hip/hip_runtime.h>
#include <hip/hip_bf16.h>
#include <cstdint>
#include <cstddef>

typedef unsigned short u16;
typedef __attribute__((ext_vector_type(8))) __bf16 bf16x8;
typedef __attribute__((ext_vector_type(4))) float f32x4;

__device__ __forceinline__ u16 f2b(float f) {
  __hip_bfloat16 h = __float2bfloat16(f);
  return *reinterpret_cast<u16*>(&h);
}
__device__ __forceinline__ uint32_t pk2(float a, float b) {
  __hip_bfloat162 h = __float22bfloat162_rn(make_float2(a, b));
  return *reinterpret_cast<uint32_t*>(&h);
}
__device__ __forceinline__ float b2f(u16 u) {
  union { float f; uint32_t i; } x; x.i = ((uint32_t)u) << 16; return x.f;
}
__device__ __forceinline__ f32x4 mfma16(bf16x8 a, bf16x8 b, f32x4 c) {
  return __builtin_amdgcn_mfma_f32_16x16x32_bf16(a, b, c, 0, 0, 0);
}
__device__ __forceinline__ void async16(const void* g, void* l) {
  __builtin_amdgcn_global_load_lds((const __attribute__((address_space(1))) uint32_t*)g,
                                   (__attribute__((address_space(3))) uint32_t*)l, 16, 0, 0);
}

// ---------------------------------------------------------------------------
// Weight conversion: fc_w1 (256x8000) permuted k: out[j][t*32+c2] = w[j][c2*250+t]
__global__ __launch_bounds__(256) void w1_perm(const float* __restrict__ w,
                                               u16* __restrict__ o) {
  __shared__ float L[8000];
  int j = blockIdx.x, tid = threadIdx.x;
  for (int i = tid; i < 8000; i += 256) L[i] = w[(size_t)j * 8000 + i];
  __syncthreads();
  for (int i = tid; i < 8000; i += 256) {
    int tt = i >> 5, c2 = i & 31;
    o[(size_t)j * 8000 + i] = f2b(L[c2 * 250 + tt]);
  }
}

struct CvtArgs {
  const float* src[13];
  void* dst[13];
  int cum[14];
  int kind[13];  // 0=f2b copy, 1=w2 permute, 2=w1 zero-pad, 3=float copy
};
__global__ __launch_bounds__(256) void f2b_multi(CvtArgs a, float* stats) {
  int i = blockIdx.x * 256 + threadIdx.x;
  if (blockIdx.x == 0 && threadIdx.x < 128) stats[threadIdx.x] = 0.f;
  int seg = 0;
  #pragma unroll
  for (int s = 1; s < 13; ++s) if (i >= a.cum[s]) seg = s;
  if (i < a.cum[13]) {
    int off = i - a.cum[seg];
    int kind = a.kind[seg];
    const float* src = a.src[seg];
    if (kind == 0) {
      ((u16*)a.dst[seg])[off] = f2b(src[off]);
    } else if (kind == 1) {
      int c2 = off / 96, rem = off - c2 * 96, kk = rem >> 5, c1 = rem & 31;
      ((u16*)a.dst[seg])[off] = f2b(src[(c2 * 32 + c1) * 3 + kk]);
    } else if (kind == 2) {
      int c1 = off >> 5, k = off & 31;
      ((u16*)a.dst[seg])[off] = f2b(k < 5 ? src[c1 * 5 + k] : 0.f);
    } else {
      ((float*)a.dst[seg])[off] = src[off];
    }
  }
}

// ---------------------------------------------------------------------------
// Fused conv1 (bf16 MFMA via zero-padded im2col) + conv2 (bf16 MFMA).
// One block per scan row. x out layout: x[row][t*32 + c2] (matches perm fc_w1)
__global__ __launch_bounds__(256) void conv_fused(
    const float* __restrict__ scan, const u16* __restrict__ w1g,
    const float* __restrict__ cb1, const u16* __restrict__ w2g,
    const float* __restrict__ cb2, u16* __restrict__ x, int row0) {
  __shared__ float s[260];
  __shared__ __align__(16) u16 A1[256 * 40];   // im2col [p][k], stride 40
  __shared__ __align__(16) u16 h1T[258 * 40];  // [p][c1], stride 40
  int tid = threadIdx.x;
  int lane = tid & 63, wv = tid >> 6;
  int l15 = lane & 15, quad = lane >> 4;
  s[tid] = scan[(size_t)(row0 + blockIdx.x) * 256 + tid];
  if (tid < 4) s[256 + tid] = 0.f;
  if (tid < 80) h1T[256 * 40 + tid] = 0;  // zero rows 256,257
  // fragments from global (L1/L2-hot across blocks)
  bf16x8 w1f[2];  // conv1 A-operand: m=c1 rows
  w1f[0] = *(const bf16x8*)&w1g[l15 * 32 + quad * 8];
  w1f[1] = *(const bf16x8*)&w1g[(16 + l15) * 32 + quad * 8];
  bf16x8 w2f[2][3];  // conv2 A-operand: m=c2 rows
  #pragma unroll
  for (int i = 0; i < 2; ++i)
    #pragma unroll
    for (int kk = 0; kk < 3; ++kk)
      w2f[i][kk] = *(const bf16x8*)&w2g[(i * 16 + l15) * 96 + kk * 32 + quad * 8];
  float cb1v[2][4], cb2v[2][4];
  #pragma unroll
  for (int i = 0; i < 2; ++i)
    #pragma unroll
    for (int r = 0; r < 4; ++r) {
      cb1v[i][r] = cb1[i * 16 + quad * 4 + r];
      cb2v[i][r] = cb2[i * 16 + quad * 4 + r];
    }
  __syncthreads();
  {  // im2col: row p=tid, k 0..4 = s[p+k], rest zero
    union { bf16x8 v; u16 u[8]; } pk;
    #pragma unroll
    for (int k = 0; k < 5; ++k) pk.u[k] = f2b(s[tid + k]);
    pk.u[5] = 0; pk.u[6] = 0; pk.u[7] = 0;
    *(bf16x8*)&A1[tid * 40] = pk.v;
    uint4 z = make_uint4(0, 0, 0, 0);
    *(uint4*)&A1[tid * 40 + 8] = z;
    *(uint4*)&A1[tid * 40 + 16] = z;
    *(uint4*)&A1[tid * 40 + 24] = z;
  }
  __syncthreads();
  // conv1 MFMA: D[c1][p] = sum_k w1g[c1][k] * A1[p][k]
  f32x4 zero = {0.f, 0.f, 0.f, 0.f};
  {
    f32x4 acc1[4][2];
    #pragma unroll
    for (int nt = 0; nt < 4; ++nt) { acc1[nt][0] = zero; acc1[nt][1] = zero; }
    #pragma unroll
    for (int nt = 0; nt < 4; ++nt) {
      int p = (wv * 4 + nt) * 16 + l15;
      bf16x8 bfr = *(const bf16x8*)&A1[p * 40 + quad * 8];
      acc1[nt][0] = mfma16(w1f[0], bfr, acc1[nt][0]);
      acc1[nt][1] = mfma16(w1f[1], bfr, acc1[nt][1]);
    }
    // epilogue: h1T[p][c1] = relu(acc + b1), c1 = mt*16+quad*4+r, p = nt-tile
    #pragma unroll
    for (int nt = 0; nt < 4; ++nt) {
      int p = (wv * 4 + nt) * 16 + l15;
      #pragma unroll
      for (int mt = 0; mt < 2; ++mt) {
        float v0 = fmaxf(acc1[nt][mt][0] + cb1v[mt][0], 0.f);
        float v1 = fmaxf(acc1[nt][mt][1] + cb1v[mt][1], 0.f);
        float v2 = fmaxf(acc1[nt][mt][2] + cb1v[mt][2], 0.f);
        float v3 = fmaxf(acc1[nt][mt][3] + cb1v[mt][3], 0.f);
        uint2 u; u.x = pk2(v0, v1); u.y = pk2(v2, v3);
        *(uint2*)&h1T[p * 40 + mt * 16 + quad * 4] = u;
      }
    }
  }
  __syncthreads();
  // conv2 MFMA: D[c2][t] = sum_{kk,c1} w2[c2][kk*32+c1] * h1T[t+kk][c1]
  f32x4 acc2[4][2];
  #pragma unroll
  for (int jj = 0; jj < 4; ++jj) { acc2[jj][0] = zero; acc2[jj][1] = zero; }
  #pragma unroll
  for (int kk = 0; kk < 3; ++kk) {
    #pragma unroll
    for (int jj = 0; jj < 4; ++jj) {
      int t = (wv * 4 + jj) * 16 + l15 + kk;
      bf16x8 h = *(const bf16x8*)&h1T[t * 40 + quad * 8];
      acc2[jj][0] = mfma16(w2f[0][kk], h, acc2[jj][0]);
      acc2[jj][1] = mfma16(w2f[1][kk], h, acc2[jj][1]);
    }
  }
  // epilogue: direct store x[t*32 + c2], c2 = i*16+quad*4+r contiguous
  u16* xr = x + (size_t)blockIdx.x * 8000;
  #pragma unroll
  for (int jj = 0; jj < 4; ++jj) {
    int t = (wv * 4 + jj) * 16 + l15;
    if (t < 250) {
      #pragma unroll
      for (int i = 0; i < 2; ++i) {
        float v0 = fmaxf(acc2[jj][i][0] + cb2v[i][0], 0.f);
        float v1 = fmaxf(acc2[jj][i][1] + cb2v[i][1], 0.f);
        float v2 = fmaxf(acc2[jj][i][2] + cb2v[i][2], 0.f);
        float v3 = fmaxf(acc2[jj][i][3] + cb2v[i][3], 0.f);
        uint2 u; u.x = pk2(v0, v1); u.y = pk2(v2, v3);
        *(uint2*)&xr[t * 32 + i * 16 + quad * 4] = u;
      }
    }
  }
}

// ---------------------------------------------------------------------------
// Generic NT bf16 MFMA GEMM, BK=64 stages, double-buffered LDS with depth-1
// async prefetch, XOR-swizzled chunks. out[m][n] = act(sum_k A[m][k]*W[n][k]+b)
// lda = A row stride, ldw = W row stride (they can differ!).
// MODE 0: fp32 raw (split-K). 1: +bias relu bf16. 2: +bias leaky bf16. 3: raw bf16
template <int MODE>
__global__ __launch_bounds__(256) void gemm_bt(
    const u16* __restrict__ A, int lda, const u16* __restrict__ W, int ldw,
    const float* __restrict__ bias, float* __restrict__ outF,
    u16* __restrict__ outB, int ldo, int nst, int wq_sel, int a_sel,
    size_t out_zoff) {
  __shared__ __align__(16) u16 As[2][128 * 64];
  __shared__ __align__(16) u16 Bs[2][128 * 64];
  int tid = threadIdx.x;
  int m0 = blockIdx.y * 128, n0 = blockIdx.x * 128;
  if (wq_sel) W += (size_t)(blockIdx.y >> 5) * wq_sel;
  if (a_sel) A += (size_t)(blockIdx.x >> 1) * a_sel;
  int kbase = blockIdx.z * nst * 64;
  if (MODE == 0) outF += (size_t)blockIdx.z * out_zoff;
  const u16* Ap = A + (size_t)m0 * lda + kbase;
  const u16* Wp = W + (size_t)n0 * ldw + kbase;
  int lane = tid & 63, wv = tid >> 6;
  int l15 = lane & 15, quad = lane >> 4;
  int wm = (wv >> 1) * 64, wn = (wv & 1) * 64;
  f32x4 zero = {0.f, 0.f, 0.f, 0.f};
  f32x4 acc[4][4];
  #pragma unroll
  for (int i = 0; i < 4; ++i)
    #pragma unroll
    for (int j = 0; j < 4; ++j) acc[i][j] = zero;

  int srow[4], soff[4], sdst[4];
  #pragma unroll
  for (int it = 0; it < 4; ++it) {
    int c = it * 256 + tid;
    int row = c >> 3, slot = c & 7;
    srow[it] = row;
    soff[it] = ((slot ^ (row & 7)) * 8);
    sdst[it] = c * 8;
  }
  int rslot[2];
  rslot[0] = ((quad ^ (l15 & 7)) * 8);
  rslot[1] = (((4 + quad) ^ (l15 & 7)) * 8);

  #pragma unroll 1
  for (int st = 0; st < nst; ++st) {
    if (st == 0) {
      #pragma unroll
      for (int it = 0; it < 4; ++it) {
        async16(Ap + (size_t)srow[it] * lda + soff[it], &As[0][sdst[it]]);
        async16(Wp + (size_t)srow[it] * ldw + soff[it], &Bs[0][sdst[it]]);
      }
    }
    __syncthreads();
    if (st + 1 < nst) {
      const u16* An = Ap + (st + 1) * 64;
      const u16* Wn = Wp + (st + 1) * 64;
      u16* Ad = &As[(st + 1) & 1][0];
      u16* Bd = &Bs[(st + 1) & 1][0];
      #pragma unroll
      for (int it = 0; it < 4; ++it) {
        async16(An + (size_t)srow[it] * lda + soff[it], Ad + sdst[it]);
        async16(Wn + (size_t)srow[it] * ldw + soff[it], Bd + sdst[it]);
      }
    }
    const u16* Ab = &As[st & 1][0];
    const u16* Bb = &Bs[st & 1][0];
    #pragma unroll
    for (int s = 0; s < 2; ++s) {
      bf16x8 af[4], bfr[4];
      #pragma unroll
      for (int i = 0; i < 4; ++i)
        af[i] = *(const bf16x8*)&Ab[(wm + i * 16 + l15) * 64 + rslot[s]];
      #pragma unroll
      for (int j = 0; j < 4; ++j)
        bfr[j] = *(const bf16x8*)&Bb[(wn + j * 16 + l15) * 64 + rslot[s]];
      #pragma unroll
      for (int i = 0; i < 4; ++i)
        #pragma unroll
        for (int j = 0; j < 4; ++j) acc[i][j] = mfma16(af[i], bfr[j], acc[i][j]);
    }
  }
  #pragma unroll
  for (int i = 0; i < 4; ++i) {
    int mb = m0 + wm + i * 16 + quad * 4;
    #pragma unroll
    for (int j = 0; j < 4; ++j) {
      int n = n0 + wn + j * 16 + l15;
      float bv_ = (MODE == 1 || MODE == 2) ? bias[n] : 0.f;
      #pragma unroll
      for (int r = 0; r < 4; ++r) {
        float v = acc[i][j][r];
        if (MODE == 0) {
          outF[(size_t)(mb + r) * ldo + n] = v;
        } else {
          v += bv_;
          if (MODE == 1) v = fmaxf(v, 0.f);
          if (MODE == 2) v = v >= 0.f ? v : 0.01f * v;
          outB[(size_t)(mb + r) * ldo + n] = f2b(v);
        }
      }
    }
  }
}

// ---------------------------------------------------------------------------
// fc2 (relu(sum hparts + b1) @ w2^T + b2) + build inps rows + batch-stat partials
__global__ __launch_bounds__(256) void fc2_stats(
    const float* __restrict__ hparts, const float* __restrict__ b1,
    const float* __restrict__ w2, const float* __restrict__ b2,
    const float* __restrict__ obs, const float* __restrict__ acts,
    float* __restrict__ inps, float* __restrict__ stats) {
  __shared__ float hL[32 * 260];
  __shared__ float w2L[10 * 260];
  __shared__ float b1L[256];
  __shared__ float ipL[32 * 61];
  int tid = threadIdx.x, r0 = blockIdx.x * 32;
  b1L[tid] = b1[tid];
  for (int i = tid; i < 2560; i += 256) w2L[(i >> 8) * 260 + (i & 255)] = w2[i];
  for (int i = tid; i < 32 * 48; i += 256) {
    int r = i / 48, f = i - r * 48;
    ipL[r * 61 + f] = obs[(size_t)(r0 + r) * 48 + f];
  }
  if (tid < 64) {
    int r = tid >> 1, f = tid & 1;
    ipL[r * 61 + 48 + f] = acts[(size_t)(r0 + r) * 2 + f];
  }
  __syncthreads();
  const size_t HS = (size_t)12288 * 256;
  for (int i = tid; i < 32 * 256; i += 256) {
    int r = i >> 8, c = i & 255;
    size_t g = (size_t)(r0 + r) * 256 + c;
    float v = b1L[c] + hparts[g] + hparts[g + HS] + hparts[g + 2 * HS] +
              hparts[g + 3 * HS] + hparts[g + 4 * HS];
    hL[r * 260 + c] = fmaxf(v, 0.f);
  }
  __syncthreads();
  {
    int r = tid >> 3, ob = tid & 7;
    for (int o = ob; o < 10; o += 8) {
      float a = 0.f;
      #pragma unroll 8
      for (int c = 0; c < 256; ++c) a += hL[r * 260 + c] * w2L[o * 260 + c];
      ipL[r * 61 + 50 + o] = a + b2[o];
    }
  }
  __syncthreads();
  for (int i = tid; i < 32 * 60; i += 256) {
    int r = i / 60, f = i - r * 60;
    inps[(size_t)(r0 + r) * 64 + f] = ipL[r * 61 + f];
  }
  if (tid < 60) {
    float s = 0.f, s2 = 0.f;
    for (int r = 0; r < 32; ++r) {
      float v = ipL[r * 61 + tid];
      s += v; s2 += v * v;
    }
    atomicAdd(&stats[tid], s);
    atomicAdd(&stats[64 + tid], s2);
  }
}

// ---------------------------------------------------------------------------
// normalize + enc (60->128) + leaky -> sa (bf16)
__global__ __launch_bounds__(256) void enc_kernel(
    const float* __restrict__ inps, const float* __restrict__ stats,
    const float* __restrict__ enc_w, const float* __restrict__ enc_b,
    u16* __restrict__ sab) {
  __shared__ float ewL[128 * 61];
  __shared__ float nrm[32 * 61];
  __shared__ float ebL[128];
  __shared__ float muL[60], ivL[60];
  int tid = threadIdx.x, r0 = blockIdx.x * 32;
  if (tid < 128) ebL[tid] = enc_b[tid];
  if (tid < 60) {
    float s = stats[tid], s2 = stats[64 + tid];
    float mu = s * (1.f / 12288.f);
    float var = s2 * (1.f / 12288.f) - mu * mu;
    muL[tid] = mu;
    ivL[tid] = rsqrtf(var + 1e-5f);
  }
  for (int i = tid; i < 128 * 60; i += 256) {
    int h = i / 60, f = i - h * 60;
    ewL[h * 61 + f] = enc_w[i];
  }
  __syncthreads();
  for (int i = tid; i < 32 * 60; i += 256) {
    int r = i / 60, f = i - r * 60;
    nrm[r * 61 + f] = (inps[(size_t)(r0 + r) * 64 + f] - muL[f]) * ivL[f];
  }
  __syncthreads();
  for (int i = tid; i < 32 * 128; i += 256) {
    int r = i >> 7, h = i & 127;
    float a = ebL[h];
    #pragma unroll 4
    for (int f = 0; f < 60; ++f) a += nrm[r * 61 + f] * ewL[h * 61 + f];
    a = a >= 0.f ? a : 0.01f * a;
    sab[(size_t)(r0 + r) * 128 + h] = f2b(a);
  }
}

// ---------------------------------------------------------------------------
// attention combine: per-b softmax over other agents + emb = [sa | other] (bf16)
__global__ __launch_bounds__(128) void attn_combine(
    const u16* __restrict__ qb, const u16* __restrict__ keysb,
    const u16* __restrict__ valsb, const u16* __restrict__ sab,
    u16* __restrict__ emb) {
  __shared__ float qL[3][128], kL[3][128], vL[3][128];
  __shared__ float lg[3][8][3], wgt[3][8][3];
  int b = blockIdx.x, t = threadIdx.x;
  #pragma unroll
  for (int o = 0; o < 3; ++o) {
    size_t base = (size_t)(o * 4096 + b) * 128 + t;
    qL[o][t] = b2f(qb[base]);
    kL[o][t] = b2f(keysb[base]);
    vL[o][t] = b2f(valsb[base]);
  }
  __syncthreads();
  if (t < 72) {
    int g = t / 24, n = (t / 3) % 8, o = t % 3;
    float a = 0.f;
    #pragma unroll
    for (int d = 0; d < 16; ++d) a += qL[g][n * 16 + d] * kL[o][n * 16 + d];
    lg[g][n][o] = (o == g) ? -1e30f : a * 0.25f;
  }
  __syncthreads();
  if (t < 24) {
    int g = t / 8, n = t % 8;
    float m = fmaxf(fmaxf(lg[g][n][0], lg[g][n][1]), lg[g][n][2]);
    float e0 = expf(lg[g][n][0] - m), e1 = expf(lg[g][n][1] - m),
          e2 = expf(lg[g][n][2] - m);
    float inv = 1.f / (e0 + e1 + e2);
    wgt[g][n][0] = e0 * inv; wgt[g][n][1] = e1 * inv; wgt[g][n][2] = e2 * inv;
  }
  __syncthreads();
  int n = t >> 4, d = t & 15;
  #pragma unroll
  for (int g = 0; g < 3; ++g) {
    float o_ = wgt[g][n][0] * vL[0][n * 16 + d] +
               wgt[g][n][1] * vL[1][n * 16 + d] +
               wgt[g][n][2] * vL[2][n * 16 + d];
    size_t rbase = (size_t)(g * 4096 + b) * 256;
    emb[rbase + 128 + t] = f2b(o_);
    emb[rbase + t] = sab[(size_t)(g * 4096 + b) * 128 + t];
  }
}

// ---------------------------------------------------------------------------
// final layer on combined t2ab (stride 512): q1 cols 0..255, q2 cols 256..511
__global__ __launch_bounds__(256) void final_dot(
    const u16* __restrict__ t2ab, const float* __restrict__ w3a,
    const float* __restrict__ b3a, const float* __restrict__ w3b,
    const float* __restrict__ b3b, float* __restrict__ out) {
  int wv = threadIdx.x >> 6, lane = threadIdx.x & 63;
  int row = blockIdx.x * 4 + wv;
  float sa_ = 0.f, sb_ = 0.f;
  #pragma unroll
  for (int e = 0; e < 4; ++e) {
    int c = lane * 4 + e;
    sa_ += b2f(t2ab[(size_t)row * 512 + c]) * w3a[c];
    sb_ += b2f(t2ab[(size_t)row * 512 + 256 + c]) * w3b[c];
  }
  #pragma unroll
  for (int off = 32; off; off >>= 1) {
    sa_ += __shfl_down(sa_, off);
    sb_ += __shfl_down(sb_, off);
  }
  if (lane == 0) {
    out[row] = sa_ + b3a[0];
    out[12288 + row] = sb_ + b3b[0];
  }
}

// ---------------------------------------------------------------------------
extern "C" void kernel_launch(void* const* d_in, const int* in_sizes, int n_in,
                              void* d_out, int out_size, void* d_ws,
                              size_t ws_size, hipStream_t stream) {
  const float* obs  = (const float*)d_in[0];
  const float* acts = (const float*)d_in[1];
  const float* scan = (const float*)d_in[2];
  const float* cw1  = (const float*)d_in[3];
  const float* cb1  = (const float*)d_in[4];
  const float* cw2  = (const float*)d_in[5];
  const float* cb2  = (const float*)d_in[6];
  const float* fw1  = (const float*)d_in[7];
  const float* fb1  = (const float*)d_in[8];
  const float* fw2  = (const float*)d_in[9];
  const float* fb2  = (const float*)d_in[10];
  const float* encw = (const float*)d_in[11];
  const float* encb = (const float*)d_in[12];
  const float* Wk   = (const float*)d_in[13];
  const float* Wv   = (const float*)d_in[14];
  const float* bv   = (const float*)d_in[15];
  const float* Wq   = (const float*)d_in[16];
  const float* q1w1 = (const float*)d_in[17];
  const float* q1b1 = (const float*)d_in[18];
  const float* q1w2 = (const float*)d_in[19];
  const float* q1b2 = (const float*)d_in[20];
  const float* q1w3 = (const float*)d_in[21];
  const float* q1b3 = (const float*)d_in[22];
  const float* q2w1 = (const float*)d_in[23];
  const float* q2b1 = (const float*)d_in[24];
  const float* q2w2 = (const float*)d_in[25];
  const float* q2b2 = (const float*)d_in[26];
  const float* q2w3 = (const float*)d_in[27];
  const float* q2b3 = (const float*)d_in[28];
  float* out = (float*)d_out;
  char* ws = (char*)d_ws;
  if (ws_size < 166016000u) return;

  // persistent region
  u16*   x     = (u16*)(ws + 0);           // slab: 6144*8000 bf16
  u16*   w1b   = (u16*)(ws + 98304000);    // 256*8000 bf16
  float* hpart = (float*)(ws + 102400000); // 5 * 12288*256 fp32
  float* stats = (float*)(ws + 165314560);
  u16*   wkb   = (u16*)(ws + 165315584);
  u16*   wvb   = (u16*)(ws + 165348352);
  u16*   wqb   = (u16*)(ws + 165381120);
  u16*   m1ab  = (u16*)(ws + 165479424);   // 512x256 bf16 (q1w1;q2w1)
  u16*   m2ab  = (u16*)(ws + 165741568);   // 512x256 bf16 (q1w2;q2w2)
  u16*   w2g   = (u16*)(ws + 166003712);   // 32*96 conv2 weights
  u16*   w1g   = (u16*)(ws + 166009856);   // 32*32 conv1 im2col weights
  float* bc1   = (float*)(ws + 166011904); // 512 f32 (q1b1;q2b1)
  float* bc2   = (float*)(ws + 166013952); // 512 f32 (q1b2;q2b2)
  // region aliasing x (dead after the last fc1 GEMM)
  float* inps  = (float*)(ws + 0);
  u16*   sab   = (u16*)(ws + 3145728);
  u16*   keysb = (u16*)(ws + 6291456);
  u16*   valsb = (u16*)(ws + 9437184);
  u16*   qb    = (u16*)(ws + 12582912);
  u16*   embb  = (u16*)(ws + 15728640);    // 12288*256 bf16
  u16*   t1ab  = (u16*)(ws + 22020096);    // 12288*512 bf16
  u16*   t2ab  = (u16*)(ws + 34603008);    // 12288*512 bf16

  w1_perm<<<256, 256, 0, stream>>>(fw1, w1b);
  CvtArgs ca;
  const float* srcs[13] = {Wk, Wv, Wq, q1w1, q2w1, q1w2, q2w2, cw2, cw1,
                           q1b1, q2b1, q1b2, q2b2};
  void* dsts[13] = {wkb, wvb, wqb, m1ab, m1ab + 65536, m2ab, m2ab + 65536,
                    w2g, w1g, bc1, bc1 + 256, bc2, bc2 + 256};
  const int sz[13] = {16384, 16384, 49152, 65536, 65536, 65536, 65536,
                      3072, 1024, 256, 256, 256, 256};
  const int kinds[13] = {0, 0, 0, 0, 0, 0, 0, 1, 2, 3, 3, 3, 3};
  int cum = 0;
  ca.cum[0] = 0;
  for (int i = 0; i < 13; ++i) {
    ca.src[i] = srcs[i]; ca.dst[i] = dsts[i]; ca.kind[i] = kinds[i];
    cum += sz[i]; ca.cum[i + 1] = cum;
  }
  f2b_multi<<<(cum + 255) / 256, 256, 0, stream>>>(ca, stats);

  // conv + fc1 in 2 row slabs
  for (int s = 0; s < 2; ++s) {
    conv_fused<<<6144, 256, 0, stream>>>(scan, w1g, cb1, w2g, cb2, x, s * 6144);
    gemm_bt<0><<<dim3(2, 48, 5), 256, 0, stream>>>(
        x, 8000, w1b, 8000, nullptr, hpart + (size_t)s * 6144 * 256, nullptr,
        256, 25, 0, 0, (size_t)12288 * 256);
  }
  fc2_stats<<<384, 256, 0, stream>>>(hpart, fb1, fw2, fb2, obs, acts, inps, stats);
  enc_kernel<<<384, 256, 0, stream>>>(inps, stats, encw, encb, sab);
  gemm_bt<3><<<dim3(1, 96, 1), 256, 0, stream>>>(sab, 128, wkb, 128, nullptr,
                                                 nullptr, keysb, 128, 2, 0, 0, 0);
  gemm_bt<2><<<dim3(1, 96, 1), 256, 0, stream>>>(sab, 128, wvb, 128, bv, nullptr,
                                                 valsb, 128, 2, 0, 0, 0);
  gemm_bt<3><<<dim3(1, 96, 1), 256, 0, stream>>>(sab, 128, wqb, 128, nullptr,
                                                 nullptr, qb, 128, 2, 16384, 0, 0);
  attn_combine<<<4096, 128, 0, stream>>>(qb, keysb, valsb, sab, embb);
  gemm_bt<1><<<dim3(4, 96, 1), 256, 0, stream>>>(embb, 256, m1ab, 256, bc1,
                                                 nullptr, t1ab, 512, 4, 0, 0, 0);
  gemm_bt<1><<<dim3(4, 96, 1), 256, 0, stream>>>(t1ab, 512, m2ab, 256, bc2,
                                                 nullptr, t2ab, 512, 4, 0, 256, 0);
  final_dot<<<3072, 256, 0, stream>>>(t2ab, q1w3, q1b3, q2w3, q2b3, out);
}